// Round 2
// baseline (5087.360 us; speedup 1.0000x reference)
//
#include <hip/hip_runtime.h>

#define N_NODES 50000
#define DIM 128
#define D4 32            // DIM/4
#define N_EDGES 800000
#define N_LAYERS 3
#define BN_EPS 1e-5f

__device__ __forceinline__ float4 f4fma(float a, const float4& b, const float4& c) {
    return make_float4(fmaf(a, b.x, c.x), fmaf(a, b.y, c.y),
                       fmaf(a, b.z, c.z), fmaf(a, b.w, c.w));
}

// ---------------- edge scatter: agg[dst] += w * h[src] ----------------
__global__ __launch_bounds__(256) void scatter_kernel(
    const float* __restrict__ h, const int* __restrict__ src,
    const int* __restrict__ dst, const float* __restrict__ ew,
    float* __restrict__ agg)
{
    long long tid = (long long)blockIdx.x * 256 + threadIdx.x;
    int e = (int)(tid >> 5);
    if (e >= N_EDGES) return;
    int lane = (int)(tid & 31);
    int s = src[e], d = dst[e];
    float w = ew[e];
    float4 v = reinterpret_cast<const float4*>(h)[(size_t)s * D4 + lane];
    float* out = agg + (size_t)d * DIM + lane * 4;
    unsafeAtomicAdd(out + 0, w * v.x);
    unsafeAtomicAdd(out + 1, w * v.y);
    unsafeAtomicAdd(out + 2, w * v.z);
    unsafeAtomicAdd(out + 3, w * v.w);
}

// ---------------- GEMM: out = f(in) @ W + bias, + column stats ----------------
// MODE 0: in = A + B          (GEMM1: r = h + agg)
// MODE 1: in = relu(A*sc+sh)  (GEMM2: BN1+ReLU fused on input)
template<int MODE>
__global__ __launch_bounds__(256) void gemm_kernel(
    const float* __restrict__ A, const float* __restrict__ B,
    const float* __restrict__ scale, const float* __restrict__ shift,
    const float* __restrict__ W, const float* __restrict__ bias,
    float* __restrict__ out, float* __restrict__ gsum, float* __restrict__ gsq)
{
    __shared__ float4 Rl[64][D4];   // 32 KB input tile
    const int t  = threadIdx.x;
    const int cg = t & 31;          // float4 column group (output cols 4*cg..4*cg+3)
    const int rg = t >> 5;          // 0..7
    const int row0 = blockIdx.x * 64;

    const float4* A4 = reinterpret_cast<const float4*>(A);

    if (MODE == 0) {
        const float4* B4 = reinterpret_cast<const float4*>(B);
        #pragma unroll
        for (int j = 0; j < 8; j++) {
            int r = rg + j * 8;
            int row = row0 + r;
            float4 v = make_float4(0.f, 0.f, 0.f, 0.f);
            if (row < N_NODES) {
                float4 a = A4[(size_t)row * D4 + cg];
                float4 b = B4[(size_t)row * D4 + cg];
                v = make_float4(a.x + b.x, a.y + b.y, a.z + b.z, a.w + b.w);
            }
            Rl[r][cg] = v;
        }
    } else {
        float4 sc = reinterpret_cast<const float4*>(scale)[cg];
        float4 sh = reinterpret_cast<const float4*>(shift)[cg];
        #pragma unroll
        for (int j = 0; j < 8; j++) {
            int r = rg + j * 8;
            int row = row0 + r;
            float4 v = make_float4(0.f, 0.f, 0.f, 0.f);
            if (row < N_NODES) {
                float4 a = A4[(size_t)row * D4 + cg];
                v.x = fmaxf(fmaf(a.x, sc.x, sh.x), 0.f);
                v.y = fmaxf(fmaf(a.y, sc.y, sh.y), 0.f);
                v.z = fmaxf(fmaf(a.z, sc.z, sh.z), 0.f);
                v.w = fmaxf(fmaf(a.w, sc.w, sh.w), 0.f);
            }
            Rl[r][cg] = v;
        }
    }
    __syncthreads();

    const float4* W4 = reinterpret_cast<const float4*>(W);
    float4 bv = reinterpret_cast<const float4*>(bias)[cg];
    float4 acc[8];
    #pragma unroll
    for (int i = 0; i < 8; i++) acc[i] = bv;

    for (int k = 0; k < DIM; k += 4) {
        float4 w0 = W4[(k + 0) * D4 + cg];
        float4 w1 = W4[(k + 1) * D4 + cg];
        float4 w2 = W4[(k + 2) * D4 + cg];
        float4 w3 = W4[(k + 3) * D4 + cg];
        #pragma unroll
        for (int i = 0; i < 8; i++) {
            float4 rv = Rl[rg * 8 + i][k >> 2];
            acc[i] = f4fma(rv.x, w0, acc[i]);
            acc[i] = f4fma(rv.y, w1, acc[i]);
            acc[i] = f4fma(rv.z, w2, acc[i]);
            acc[i] = f4fma(rv.w, w3, acc[i]);
        }
    }

    float4* out4 = reinterpret_cast<float4*>(out);
    #pragma unroll
    for (int i = 0; i < 8; i++) {
        int row = row0 + rg * 8 + i;
        if (row < N_NODES) out4[(size_t)row * D4 + cg] = acc[i];
    }

    // per-column partial sums (exclude padded rows)
    float4 psum = make_float4(0.f, 0.f, 0.f, 0.f);
    float4 psq  = make_float4(0.f, 0.f, 0.f, 0.f);
    #pragma unroll
    for (int i = 0; i < 8; i++) {
        int row = row0 + rg * 8 + i;
        if (row < N_NODES) {
            psum.x += acc[i].x; psum.y += acc[i].y; psum.z += acc[i].z; psum.w += acc[i].w;
            psq.x += acc[i].x * acc[i].x; psq.y += acc[i].y * acc[i].y;
            psq.z += acc[i].z * acc[i].z; psq.w += acc[i].w * acc[i].w;
        }
    }
    __syncthreads();                       // done reading Rl, reuse as scratch
    float4* red = &Rl[0][0];
    red[t]       = psum;
    red[256 + t] = psq;
    __syncthreads();
    if (t < 32) {
        float4 s = make_float4(0.f, 0.f, 0.f, 0.f);
        float4 q = make_float4(0.f, 0.f, 0.f, 0.f);
        #pragma unroll
        for (int r = 0; r < 8; r++) {
            float4 a = red[r * 32 + t];
            float4 b = red[256 + r * 32 + t];
            s.x += a.x; s.y += a.y; s.z += a.z; s.w += a.w;
            q.x += b.x; q.y += b.y; q.z += b.z; q.w += b.w;
        }
        float* gs = gsum + t * 4;
        float* gq = gsq + t * 4;
        unsafeAtomicAdd(gs + 0, s.x); unsafeAtomicAdd(gs + 1, s.y);
        unsafeAtomicAdd(gs + 2, s.z); unsafeAtomicAdd(gs + 3, s.w);
        unsafeAtomicAdd(gq + 0, q.x); unsafeAtomicAdd(gq + 1, q.y);
        unsafeAtomicAdd(gq + 2, q.z); unsafeAtomicAdd(gq + 3, q.w);
    }
}

// ---------------- finalize BN: (sum,sumsq,gamma,beta) -> (scale,shift) ----------------
__global__ void finalize_kernel(const float* __restrict__ gsum, const float* __restrict__ gsq,
                                const float* __restrict__ g, const float* __restrict__ b,
                                float* __restrict__ scale, float* __restrict__ shift)
{
    int c = threadIdx.x;
    float mean = gsum[c] * (1.f / N_NODES);
    float var  = gsq[c] * (1.f / N_NODES) - mean * mean;
    float rstd = rsqrtf(var + BN_EPS);
    float s = g[c] * rstd;
    scale[c] = s;
    shift[c] = b[c] - mean * s;
}

// ---------------- y = relu(x*sc+sh), accumulate column stats of y ----------------
__global__ __launch_bounds__(256) void bn_apply_stats_kernel(
    const float* __restrict__ x, const float* __restrict__ scale,
    const float* __restrict__ shift, float* __restrict__ y,
    float* __restrict__ gsum, float* __restrict__ gsq)
{
    const int t = threadIdx.x;
    const int cg = t & 31;
    float4 sc = reinterpret_cast<const float4*>(scale)[cg];
    float4 sh = reinterpret_cast<const float4*>(shift)[cg];
    const float4* x4 = reinterpret_cast<const float4*>(x);
    float4* y4 = reinterpret_cast<float4*>(y);
    float4 psum = make_float4(0.f, 0.f, 0.f, 0.f);
    float4 psq  = make_float4(0.f, 0.f, 0.f, 0.f);
    const int total = N_NODES * D4;
    const int stride = gridDim.x * 256;
    for (int idx = blockIdx.x * 256 + t; idx < total; idx += stride) {
        float4 v = x4[idx];
        v.x = fmaxf(fmaf(v.x, sc.x, sh.x), 0.f);
        v.y = fmaxf(fmaf(v.y, sc.y, sh.y), 0.f);
        v.z = fmaxf(fmaf(v.z, sc.z, sh.z), 0.f);
        v.w = fmaxf(fmaf(v.w, sc.w, sh.w), 0.f);
        y4[idx] = v;
        psum.x += v.x; psum.y += v.y; psum.z += v.z; psum.w += v.w;
        psq.x += v.x * v.x; psq.y += v.y * v.y; psq.z += v.z * v.z; psq.w += v.w * v.w;
    }
    __shared__ float4 red[512];
    red[t]       = psum;
    red[256 + t] = psq;
    __syncthreads();
    if (t < 32) {
        float4 s = make_float4(0.f, 0.f, 0.f, 0.f);
        float4 q = make_float4(0.f, 0.f, 0.f, 0.f);
        #pragma unroll
        for (int r = 0; r < 8; r++) {
            float4 a = red[r * 32 + t];
            float4 b = red[256 + r * 32 + t];
            s.x += a.x; s.y += a.y; s.z += a.z; s.w += a.w;
            q.x += b.x; q.y += b.y; q.z += b.z; q.w += b.w;
        }
        float* gs = gsum + t * 4;
        float* gq = gsq + t * 4;
        unsafeAtomicAdd(gs + 0, s.x); unsafeAtomicAdd(gs + 1, s.y);
        unsafeAtomicAdd(gs + 2, s.z); unsafeAtomicAdd(gs + 3, s.w);
        unsafeAtomicAdd(gq + 0, q.x); unsafeAtomicAdd(gq + 1, q.y);
        unsafeAtomicAdd(gq + 2, q.z); unsafeAtomicAdd(gq + 3, q.w);
    }
}

// ---------------- y = relu(x*sc+sh) ----------------
__global__ __launch_bounds__(256) void bn_apply_kernel(
    const float* __restrict__ x, const float* __restrict__ scale,
    const float* __restrict__ shift, float* __restrict__ y)
{
    const int t = threadIdx.x;
    const int cg = t & 31;
    float4 sc = reinterpret_cast<const float4*>(scale)[cg];
    float4 sh = reinterpret_cast<const float4*>(shift)[cg];
    const float4* x4 = reinterpret_cast<const float4*>(x);
    float4* y4 = reinterpret_cast<float4*>(y);
    const int total = N_NODES * D4;
    const int stride = gridDim.x * 256;
    for (int idx = blockIdx.x * 256 + t; idx < total; idx += stride) {
        float4 v = x4[idx];
        v.x = fmaxf(fmaf(v.x, sc.x, sh.x), 0.f);
        v.y = fmaxf(fmaf(v.y, sc.y, sh.y), 0.f);
        v.z = fmaxf(fmaf(v.z, sc.z, sh.z), 0.f);
        v.w = fmaxf(fmaf(v.w, sc.w, sh.w), 0.f);
        y4[idx] = v;
    }
}

extern "C" void kernel_launch(void* const* d_in, const int* in_sizes, int n_in,
                              void* d_out, int out_size, void* d_ws, size_t ws_size,
                              hipStream_t stream)
{
    const float* h0    = (const float*)d_in[0];
    const int*   src   = (const int*)d_in[1];
    const int*   dst   = (const int*)d_in[2];
    const float* ew    = (const float*)d_in[3];
    const float* W1    = (const float*)d_in[4];
    const float* b1    = (const float*)d_in[5];
    const float* bn1_g = (const float*)d_in[6];
    const float* bn1_b = (const float*)d_in[7];
    const float* W2    = (const float*)d_in[8];
    const float* b2    = (const float*)d_in[9];
    const float* bna_g = (const float*)d_in[10];
    const float* bna_b = (const float*)d_in[11];
    const float* bno_g = (const float*)d_in[12];
    const float* bno_b = (const float*)d_in[13];

    float* agg   = (float*)d_ws;                          // N*D (also reused as x2)
    float* xbuf  = agg + (size_t)N_NODES * DIM;           // N*D (x1, then x_a)
    float* stats = xbuf + (size_t)N_NODES * DIM;          // 9 * 512 floats
    float* hout  = (float*)d_out;

    hipMemsetAsync(stats, 0, 9 * 512 * sizeof(float), stream);

    const int gemm_grid = (N_NODES + 63) / 64;            // 782
    const int scat_grid = (N_EDGES * 32 + 255) / 256;     // 100000

    for (int i = 0; i < N_LAYERS; i++) {
        const float* hin = (i == 0) ? h0 : hout;
        float* st1 = stats + (i * 3 + 0) * 512;  // [sum | sumsq | scale | shift]
        float* stA = stats + (i * 3 + 1) * 512;
        float* stO = stats + (i * 3 + 2) * 512;

        hipMemsetAsync(agg, 0, (size_t)N_NODES * DIM * sizeof(float), stream);
        scatter_kernel<<<scat_grid, 256, 0, stream>>>(
            hin, src + (size_t)i * N_EDGES, dst + (size_t)i * N_EDGES,
            ew + (size_t)i * N_EDGES, agg);

        gemm_kernel<0><<<gemm_grid, 256, 0, stream>>>(
            hin, agg, nullptr, nullptr,
            W1 + (size_t)i * DIM * DIM, b1 + (size_t)i * DIM,
            xbuf, st1, st1 + 128);
        finalize_kernel<<<1, 128, 0, stream>>>(st1, st1 + 128,
            bn1_g + (size_t)i * DIM, bn1_b + (size_t)i * DIM, st1 + 256, st1 + 384);

        gemm_kernel<1><<<gemm_grid, 256, 0, stream>>>(
            xbuf, nullptr, st1 + 256, st1 + 384,
            W2 + (size_t)i * DIM * DIM, b2 + (size_t)i * DIM,
            agg, stA, stA + 128);
        finalize_kernel<<<1, 128, 0, stream>>>(stA, stA + 128,
            bna_g + (size_t)i * DIM, bna_b + (size_t)i * DIM, stA + 256, stA + 384);

        bn_apply_stats_kernel<<<1024, 256, 0, stream>>>(
            agg, stA + 256, stA + 384, xbuf, stO, stO + 128);
        finalize_kernel<<<1, 128, 0, stream>>>(stO, stO + 128,
            bno_g + (size_t)i * DIM, bno_b + (size_t)i * DIM, stO + 256, stO + 384);

        bn_apply_kernel<<<1024, 256, 0, stream>>>(xbuf, stO + 256, stO + 384, hout);
    }
}

// Round 3
// 1911.000 us; speedup vs baseline: 2.6621x; 2.6621x over previous
//
#include <hip/hip_runtime.h>

#define N_NODES 50000
#define DIM 128
#define D4 32            // DIM/4
#define N_EDGES 800000
#define N_LAYERS 3
#define BN_EPS 1e-5f
#define SCAN_T 1024
#define SCAN_CH ((N_NODES + SCAN_T - 1) / SCAN_T)   // 49

__device__ __forceinline__ float4 f4fma(float a, const float4& b, const float4& c) {
    return make_float4(fmaf(a, b.x, c.x), fmaf(a, b.y, c.y),
                       fmaf(a, b.z, c.z), fmaf(a, b.w, c.w));
}

// ---------------- CSR build: histogram of dst ----------------
__global__ __launch_bounds__(256) void hist_kernel(
    const int* __restrict__ dst, int* __restrict__ counts)
{
    int e = blockIdx.x * 256 + threadIdx.x;
    if (e < N_EDGES) atomicAdd(&counts[dst[e]], 1);
}

// ---------------- CSR build: single-block exclusive scan ----------------
__global__ __launch_bounds__(SCAN_T) void scan_kernel(
    const int* __restrict__ counts, int* __restrict__ offsets,
    int* __restrict__ cursor)
{
    __shared__ int ssum[SCAN_T];
    const int t = threadIdx.x;
    const int base = t * SCAN_CH;
    int local = 0;
    for (int i = 0; i < SCAN_CH; i++) {
        int idx = base + i;
        if (idx < N_NODES) local += counts[idx];
    }
    ssum[t] = local;
    __syncthreads();
    // Hillis-Steele inclusive scan
    for (int off = 1; off < SCAN_T; off <<= 1) {
        int v = (t >= off) ? ssum[t - off] : 0;
        __syncthreads();
        ssum[t] += v;
        __syncthreads();
    }
    int running = ssum[t] - local;    // exclusive prefix of this thread's chunk
    for (int i = 0; i < SCAN_CH; i++) {
        int idx = base + i;
        if (idx < N_NODES) {
            offsets[idx] = running;
            cursor[idx]  = running;
            running += counts[idx];
        }
    }
    if (t == SCAN_T - 1) offsets[N_NODES] = ssum[SCAN_T - 1];
}

// ---------------- CSR build: fill permuted (src, weight) ----------------
__global__ __launch_bounds__(256) void fill_kernel(
    const int* __restrict__ src, const int* __restrict__ dst,
    const float* __restrict__ ew, int* __restrict__ cursor,
    int2* __restrict__ eperm)
{
    int e = blockIdx.x * 256 + threadIdx.x;
    if (e >= N_EDGES) return;
    int pos = atomicAdd(&cursor[dst[e]], 1);
    eperm[pos] = make_int2(src[e], __float_as_int(ew[e]));
}

// ---------------- aggregate: agg[n] = sum_{e: dst=n} w_e * h[src_e] ----------------
__global__ __launch_bounds__(256) void agg_kernel(
    const float* __restrict__ h, const int* __restrict__ offsets,
    const int2* __restrict__ eperm, float* __restrict__ agg)
{
    int gid = blockIdx.x * 256 + threadIdx.x;
    int node = gid >> 5;
    if (node >= N_NODES) return;
    int lane = gid & 31;
    int beg = offsets[node], end = offsets[node + 1];
    const float4* h4 = reinterpret_cast<const float4*>(h);
    float4 v = make_float4(0.f, 0.f, 0.f, 0.f);
    for (int j = beg; j < end; j++) {
        int2 e = eperm[j];
        float w = __int_as_float(e.y);
        float4 x = h4[(size_t)e.x * D4 + lane];
        v = f4fma(w, x, v);
    }
    reinterpret_cast<float4*>(agg)[(size_t)node * D4 + lane] = v;
}

// ---------------- GEMM: out = f(in) @ W + bias, + column stats ----------------
// MODE 0: in = A + B          (GEMM1: r = h + agg)
// MODE 1: in = relu(A*sc+sh)  (GEMM2: BN1+ReLU fused on input)
template<int MODE>
__global__ __launch_bounds__(256) void gemm_kernel(
    const float* __restrict__ A, const float* __restrict__ B,
    const float* __restrict__ scale, const float* __restrict__ shift,
    const float* __restrict__ W, const float* __restrict__ bias,
    float* __restrict__ out, float* __restrict__ gsum, float* __restrict__ gsq)
{
    __shared__ float4 Rl[64][D4];   // 32 KB input tile
    const int t  = threadIdx.x;
    const int cg = t & 31;          // float4 column group (output cols 4*cg..4*cg+3)
    const int rg = t >> 5;          // 0..7
    const int row0 = blockIdx.x * 64;

    const float4* A4 = reinterpret_cast<const float4*>(A);

    if (MODE == 0) {
        const float4* B4 = reinterpret_cast<const float4*>(B);
        #pragma unroll
        for (int j = 0; j < 8; j++) {
            int r = rg + j * 8;
            int row = row0 + r;
            float4 v = make_float4(0.f, 0.f, 0.f, 0.f);
            if (row < N_NODES) {
                float4 a = A4[(size_t)row * D4 + cg];
                float4 b = B4[(size_t)row * D4 + cg];
                v = make_float4(a.x + b.x, a.y + b.y, a.z + b.z, a.w + b.w);
            }
            Rl[r][cg] = v;
        }
    } else {
        float4 sc = reinterpret_cast<const float4*>(scale)[cg];
        float4 sh = reinterpret_cast<const float4*>(shift)[cg];
        #pragma unroll
        for (int j = 0; j < 8; j++) {
            int r = rg + j * 8;
            int row = row0 + r;
            float4 v = make_float4(0.f, 0.f, 0.f, 0.f);
            if (row < N_NODES) {
                float4 a = A4[(size_t)row * D4 + cg];
                v.x = fmaxf(fmaf(a.x, sc.x, sh.x), 0.f);
                v.y = fmaxf(fmaf(a.y, sc.y, sh.y), 0.f);
                v.z = fmaxf(fmaf(a.z, sc.z, sh.z), 0.f);
                v.w = fmaxf(fmaf(a.w, sc.w, sh.w), 0.f);
            }
            Rl[r][cg] = v;
        }
    }
    __syncthreads();

    const float4* W4 = reinterpret_cast<const float4*>(W);
    float4 bv = reinterpret_cast<const float4*>(bias)[cg];
    float4 acc[8];
    #pragma unroll
    for (int i = 0; i < 8; i++) acc[i] = bv;

    for (int k = 0; k < DIM; k += 4) {
        float4 w0 = W4[(k + 0) * D4 + cg];
        float4 w1 = W4[(k + 1) * D4 + cg];
        float4 w2 = W4[(k + 2) * D4 + cg];
        float4 w3 = W4[(k + 3) * D4 + cg];
        #pragma unroll
        for (int i = 0; i < 8; i++) {
            float4 rv = Rl[rg * 8 + i][k >> 2];
            acc[i] = f4fma(rv.x, w0, acc[i]);
            acc[i] = f4fma(rv.y, w1, acc[i]);
            acc[i] = f4fma(rv.z, w2, acc[i]);
            acc[i] = f4fma(rv.w, w3, acc[i]);
        }
    }

    float4* out4 = reinterpret_cast<float4*>(out);
    #pragma unroll
    for (int i = 0; i < 8; i++) {
        int row = row0 + rg * 8 + i;
        if (row < N_NODES) out4[(size_t)row * D4 + cg] = acc[i];
    }

    // per-column partial sums (exclude padded rows)
    float4 psum = make_float4(0.f, 0.f, 0.f, 0.f);
    float4 psq  = make_float4(0.f, 0.f, 0.f, 0.f);
    #pragma unroll
    for (int i = 0; i < 8; i++) {
        int row = row0 + rg * 8 + i;
        if (row < N_NODES) {
            psum.x += acc[i].x; psum.y += acc[i].y; psum.z += acc[i].z; psum.w += acc[i].w;
            psq.x += acc[i].x * acc[i].x; psq.y += acc[i].y * acc[i].y;
            psq.z += acc[i].z * acc[i].z; psq.w += acc[i].w * acc[i].w;
        }
    }
    __syncthreads();                       // done reading Rl, reuse as scratch
    float4* red = &Rl[0][0];
    red[t]       = psum;
    red[256 + t] = psq;
    __syncthreads();
    if (t < 32) {
        float4 s = make_float4(0.f, 0.f, 0.f, 0.f);
        float4 q = make_float4(0.f, 0.f, 0.f, 0.f);
        #pragma unroll
        for (int r = 0; r < 8; r++) {
            float4 a = red[r * 32 + t];
            float4 b = red[256 + r * 32 + t];
            s.x += a.x; s.y += a.y; s.z += a.z; s.w += a.w;
            q.x += b.x; q.y += b.y; q.z += b.z; q.w += b.w;
        }
        float* gs = gsum + t * 4;
        float* gq = gsq + t * 4;
        unsafeAtomicAdd(gs + 0, s.x); unsafeAtomicAdd(gs + 1, s.y);
        unsafeAtomicAdd(gs + 2, s.z); unsafeAtomicAdd(gs + 3, s.w);
        unsafeAtomicAdd(gq + 0, q.x); unsafeAtomicAdd(gq + 1, q.y);
        unsafeAtomicAdd(gq + 2, q.z); unsafeAtomicAdd(gq + 3, q.w);
    }
}

// ---------------- finalize BN: (sum,sumsq,gamma,beta) -> (scale,shift) ----------------
__global__ void finalize_kernel(const float* __restrict__ gsum, const float* __restrict__ gsq,
                                const float* __restrict__ g, const float* __restrict__ b,
                                float* __restrict__ scale, float* __restrict__ shift)
{
    int c = threadIdx.x;
    float mean = gsum[c] * (1.f / N_NODES);
    float var  = gsq[c] * (1.f / N_NODES) - mean * mean;
    float rstd = rsqrtf(var + BN_EPS);
    float s = g[c] * rstd;
    scale[c] = s;
    shift[c] = b[c] - mean * s;
}

// ---------------- y = relu(x*sc+sh), accumulate column stats of y ----------------
__global__ __launch_bounds__(256) void bn_apply_stats_kernel(
    const float* __restrict__ x, const float* __restrict__ scale,
    const float* __restrict__ shift, float* __restrict__ y,
    float* __restrict__ gsum, float* __restrict__ gsq)
{
    const int t = threadIdx.x;
    const int cg = t & 31;
    float4 sc = reinterpret_cast<const float4*>(scale)[cg];
    float4 sh = reinterpret_cast<const float4*>(shift)[cg];
    const float4* x4 = reinterpret_cast<const float4*>(x);
    float4* y4 = reinterpret_cast<float4*>(y);
    float4 psum = make_float4(0.f, 0.f, 0.f, 0.f);
    float4 psq  = make_float4(0.f, 0.f, 0.f, 0.f);
    const int total = N_NODES * D4;
    const int stride = gridDim.x * 256;
    for (int idx = blockIdx.x * 256 + t; idx < total; idx += stride) {
        float4 v = x4[idx];
        v.x = fmaxf(fmaf(v.x, sc.x, sh.x), 0.f);
        v.y = fmaxf(fmaf(v.y, sc.y, sh.y), 0.f);
        v.z = fmaxf(fmaf(v.z, sc.z, sh.z), 0.f);
        v.w = fmaxf(fmaf(v.w, sc.w, sh.w), 0.f);
        y4[idx] = v;
        psum.x += v.x; psum.y += v.y; psum.z += v.z; psum.w += v.w;
        psq.x += v.x * v.x; psq.y += v.y * v.y; psq.z += v.z * v.z; psq.w += v.w * v.w;
    }
    __shared__ float4 red[512];
    red[t]       = psum;
    red[256 + t] = psq;
    __syncthreads();
    if (t < 32) {
        float4 s = make_float4(0.f, 0.f, 0.f, 0.f);
        float4 q = make_float4(0.f, 0.f, 0.f, 0.f);
        #pragma unroll
        for (int r = 0; r < 8; r++) {
            float4 a = red[r * 32 + t];
            float4 b = red[256 + r * 32 + t];
            s.x += a.x; s.y += a.y; s.z += a.z; s.w += a.w;
            q.x += b.x; q.y += b.y; q.z += b.z; q.w += b.w;
        }
        float* gs = gsum + t * 4;
        float* gq = gsq + t * 4;
        unsafeAtomicAdd(gs + 0, s.x); unsafeAtomicAdd(gs + 1, s.y);
        unsafeAtomicAdd(gs + 2, s.z); unsafeAtomicAdd(gs + 3, s.w);
        unsafeAtomicAdd(gq + 0, q.x); unsafeAtomicAdd(gq + 1, q.y);
        unsafeAtomicAdd(gq + 2, q.z); unsafeAtomicAdd(gq + 3, q.w);
    }
}

// ---------------- y = relu(x*sc+sh) ----------------
__global__ __launch_bounds__(256) void bn_apply_kernel(
    const float* __restrict__ x, const float* __restrict__ scale,
    const float* __restrict__ shift, float* __restrict__ y)
{
    const int t = threadIdx.x;
    const int cg = t & 31;
    float4 sc = reinterpret_cast<const float4*>(scale)[cg];
    float4 sh = reinterpret_cast<const float4*>(shift)[cg];
    const float4* x4 = reinterpret_cast<const float4*>(x);
    float4* y4 = reinterpret_cast<float4*>(y);
    const int total = N_NODES * D4;
    const int stride = gridDim.x * 256;
    for (int idx = blockIdx.x * 256 + t; idx < total; idx += stride) {
        float4 v = x4[idx];
        v.x = fmaxf(fmaf(v.x, sc.x, sh.x), 0.f);
        v.y = fmaxf(fmaf(v.y, sc.y, sh.y), 0.f);
        v.z = fmaxf(fmaf(v.z, sc.z, sh.z), 0.f);
        v.w = fmaxf(fmaf(v.w, sc.w, sh.w), 0.f);
        y4[idx] = v;
    }
}

extern "C" void kernel_launch(void* const* d_in, const int* in_sizes, int n_in,
                              void* d_out, int out_size, void* d_ws, size_t ws_size,
                              hipStream_t stream)
{
    const float* h0    = (const float*)d_in[0];
    const int*   src   = (const int*)d_in[1];
    const int*   dst   = (const int*)d_in[2];
    const float* ew    = (const float*)d_in[3];
    const float* W1    = (const float*)d_in[4];
    const float* b1    = (const float*)d_in[5];
    const float* bn1_g = (const float*)d_in[6];
    const float* bn1_b = (const float*)d_in[7];
    const float* W2    = (const float*)d_in[8];
    const float* b2    = (const float*)d_in[9];
    const float* bna_g = (const float*)d_in[10];
    const float* bna_b = (const float*)d_in[11];
    const float* bno_g = (const float*)d_in[12];
    const float* bno_b = (const float*)d_in[13];

    float* agg    = (float*)d_ws;                         // N*D (also reused as x2)
    float* xbuf   = agg + (size_t)N_NODES * DIM;          // N*D (x1, then x_a)
    float* stats  = xbuf + (size_t)N_NODES * DIM;         // 9 * 512 floats
    int*   counts = (int*)(stats + 9 * 512);              // N ints
    int*   offs   = counts + N_NODES;                     // N+1 ints
    int*   cursor = offs + N_NODES + 1;                   // N ints
    int2*  eperm  = (int2*)(((uintptr_t)(cursor + N_NODES) + 15) & ~(uintptr_t)15); // E int2
    float* hout   = (float*)d_out;

    hipMemsetAsync(stats, 0, 9 * 512 * sizeof(float), stream);

    const int gemm_grid = (N_NODES + 63) / 64;            // 782
    const int edge_grid = (N_EDGES + 255) / 256;          // 3125
    const int agg_grid  = (N_NODES * 32 + 255) / 256;     // 6250

    for (int i = 0; i < N_LAYERS; i++) {
        const float* hin = (i == 0) ? h0 : hout;
        const int* srcL = src + (size_t)i * N_EDGES;
        const int* dstL = dst + (size_t)i * N_EDGES;
        const float* ewL = ew + (size_t)i * N_EDGES;
        float* st1 = stats + (i * 3 + 0) * 512;  // [sum | sumsq | scale | shift]
        float* stA = stats + (i * 3 + 1) * 512;
        float* stO = stats + (i * 3 + 2) * 512;

        // --- CSR build + gather aggregation (no float atomics) ---
        hipMemsetAsync(counts, 0, N_NODES * sizeof(int), stream);
        hist_kernel<<<edge_grid, 256, 0, stream>>>(dstL, counts);
        scan_kernel<<<1, SCAN_T, 0, stream>>>(counts, offs, cursor);
        fill_kernel<<<edge_grid, 256, 0, stream>>>(srcL, dstL, ewL, cursor, eperm);
        agg_kernel<<<agg_grid, 256, 0, stream>>>(hin, offs, eperm, agg);

        gemm_kernel<0><<<gemm_grid, 256, 0, stream>>>(
            hin, agg, nullptr, nullptr,
            W1 + (size_t)i * DIM * DIM, b1 + (size_t)i * DIM,
            xbuf, st1, st1 + 128);
        finalize_kernel<<<1, 128, 0, stream>>>(st1, st1 + 128,
            bn1_g + (size_t)i * DIM, bn1_b + (size_t)i * DIM, st1 + 256, st1 + 384);

        gemm_kernel<1><<<gemm_grid, 256, 0, stream>>>(
            xbuf, nullptr, st1 + 256, st1 + 384,
            W2 + (size_t)i * DIM * DIM, b2 + (size_t)i * DIM,
            agg, stA, stA + 128);
        finalize_kernel<<<1, 128, 0, stream>>>(stA, stA + 128,
            bna_g + (size_t)i * DIM, bna_b + (size_t)i * DIM, stA + 256, stA + 384);

        bn_apply_stats_kernel<<<1024, 256, 0, stream>>>(
            agg, stA + 256, stA + 384, xbuf, stO, stO + 128);
        finalize_kernel<<<1, 128, 0, stream>>>(stO, stO + 128,
            bno_g + (size_t)i * DIM, bno_b + (size_t)i * DIM, stO + 256, stO + 384);

        bn_apply_kernel<<<1024, 256, 0, stream>>>(xbuf, stO + 256, stO + 384, hout);
    }
}

// Round 4
// 1543.290 us; speedup vs baseline: 3.2964x; 1.2383x over previous
//
#include <hip/hip_runtime.h>

#define N_NODES 50000
#define DIM 128
#define D4 32            // DIM/4
#define N_EDGES 800000
#define N_LAYERS 3
#define BN_EPS 1e-5f
#define NBLK_SCAN ((N_NODES + 255) / 256)   // 196

__device__ __forceinline__ float4 f4fma(float a, const float4& b, const float4& c) {
    return make_float4(fmaf(a, b.x, c.x), fmaf(a, b.y, c.y),
                       fmaf(a, b.z, c.z), fmaf(a, b.w, c.w));
}

// scale/shift from raw BN stats
__device__ __forceinline__ void bn_coef(float sum, float sq, float g, float b,
                                        float& sc, float& sh) {
    float mean = sum * (1.f / N_NODES);
    float var  = sq * (1.f / N_NODES) - mean * mean;
    float rstd = rsqrtf(var + BN_EPS);
    sc = g * rstd;
    sh = b - mean * sc;
}

__device__ __forceinline__ void bn_coef4(const float* gsum, const float* gsq,
                                         const float* g, const float* b, int cg,
                                         float4& sc, float4& sh) {
    float4 s  = reinterpret_cast<const float4*>(gsum)[cg];
    float4 q  = reinterpret_cast<const float4*>(gsq)[cg];
    float4 gg = reinterpret_cast<const float4*>(g)[cg];
    float4 bb = reinterpret_cast<const float4*>(b)[cg];
    bn_coef(s.x, q.x, gg.x, bb.x, sc.x, sh.x);
    bn_coef(s.y, q.y, gg.y, bb.y, sc.y, sh.y);
    bn_coef(s.z, q.z, gg.z, bb.z, sc.z, sh.z);
    bn_coef(s.w, q.w, gg.w, bb.w, sc.w, sh.w);
}

// ---------------- CSR build: histogram of dst ----------------
__global__ __launch_bounds__(256) void hist_kernel(
    const int* __restrict__ dst, int* __restrict__ counts)
{
    int e = blockIdx.x * 256 + threadIdx.x;
    if (e < N_EDGES) atomicAdd(&counts[dst[e]], 1);
}

// ---------------- scan stage 1: per-256-chunk sums ----------------
__global__ __launch_bounds__(256) void partial_kernel(
    const int* __restrict__ counts, int* __restrict__ bsum)
{
    __shared__ int s[256];
    int idx = blockIdx.x * 256 + threadIdx.x;
    int v = (idx < N_NODES) ? counts[idx] : 0;
    s[threadIdx.x] = v;
    __syncthreads();
    #pragma unroll
    for (int off = 128; off > 0; off >>= 1) {
        if (threadIdx.x < off) s[threadIdx.x] += s[threadIdx.x + off];
        __syncthreads();
    }
    if (threadIdx.x == 0) bsum[blockIdx.x] = s[0];
}

// ---------------- scan stage 2: scan the 196 block sums ----------------
__global__ __launch_bounds__(256) void scan_small_kernel(
    const int* __restrict__ bsum, int* __restrict__ bscan, int* __restrict__ offsets)
{
    __shared__ int s[256];
    int t = threadIdx.x;
    int v = (t < NBLK_SCAN) ? bsum[t] : 0;
    s[t] = v;
    __syncthreads();
    #pragma unroll
    for (int off = 1; off < 256; off <<= 1) {
        int u = (t >= off) ? s[t - off] : 0;
        __syncthreads();
        s[t] += u;
        __syncthreads();
    }
    if (t < NBLK_SCAN) bscan[t] = s[t] - v;     // exclusive
    if (t == 255) offsets[N_NODES] = s[255];    // total (= N_EDGES)
}

// ---------------- scan stage 3: per-chunk exclusive scan + base ----------------
__global__ __launch_bounds__(256) void write_offs_kernel(
    const int* __restrict__ counts, const int* __restrict__ bscan,
    int* __restrict__ offsets, int* __restrict__ cursor)
{
    __shared__ int s[256];
    int t = threadIdx.x;
    int idx = blockIdx.x * 256 + t;
    int v = (idx < N_NODES) ? counts[idx] : 0;
    s[t] = v;
    __syncthreads();
    #pragma unroll
    for (int off = 1; off < 256; off <<= 1) {
        int u = (t >= off) ? s[t - off] : 0;
        __syncthreads();
        s[t] += u;
        __syncthreads();
    }
    int ex = s[t] - v + bscan[blockIdx.x];
    if (idx < N_NODES) { offsets[idx] = ex; cursor[idx] = ex; }
}

// ---------------- CSR build: fill permuted (src, weight) ----------------
__global__ __launch_bounds__(256) void fill_kernel(
    const int* __restrict__ src, const int* __restrict__ dst,
    const float* __restrict__ ew, int* __restrict__ cursor,
    int2* __restrict__ eperm)
{
    int e = blockIdx.x * 256 + threadIdx.x;
    if (e >= N_EDGES) return;
    int pos = atomicAdd(&cursor[dst[e]], 1);
    eperm[pos] = make_int2(src[e], __float_as_int(ew[e]));
}

// ---------------- aggregate: agg[n] = sum_{e: dst=n} w_e * h[src_e] ----------------
__global__ __launch_bounds__(256) void agg_kernel(
    const float* __restrict__ h, const int* __restrict__ offsets,
    const int2* __restrict__ eperm, float* __restrict__ agg)
{
    int gid = blockIdx.x * 256 + threadIdx.x;
    int node = gid >> 5;
    if (node >= N_NODES) return;
    int lane = gid & 31;
    int beg = offsets[node], end = offsets[node + 1];
    const float4* h4 = reinterpret_cast<const float4*>(h);
    float4 v = make_float4(0.f, 0.f, 0.f, 0.f);
    for (int j = beg; j < end; j++) {
        int2 e = eperm[j];
        float w = __int_as_float(e.y);
        float4 x = h4[(size_t)e.x * D4 + lane];
        v = f4fma(w, x, v);
    }
    reinterpret_cast<float4*>(agg)[(size_t)node * D4 + lane] = v;
}

// ---------------- GEMM: out = f(in) @ W + bias, + column stats ----------------
// MODE 0: in = A + B                    (GEMM1: r = h + agg)
// MODE 1: in = relu(BN(A; st,g,b))      (GEMM2: BN1+ReLU fused on input)
template<int MODE>
__global__ __launch_bounds__(256) void gemm_kernel(
    const float* __restrict__ A, const float* __restrict__ B,
    const float* __restrict__ st_in, const float* __restrict__ bn_g,
    const float* __restrict__ bn_b,
    const float* __restrict__ W, const float* __restrict__ bias,
    float* __restrict__ out, float* __restrict__ gsum, float* __restrict__ gsq)
{
    __shared__ float4 Rl[64][D4];   // 32 KB input tile
    const int t  = threadIdx.x;
    const int cg = t & 31;          // float4 column group
    const int rg = t >> 5;          // 0..7
    const int row0 = blockIdx.x * 64;

    const float4* A4 = reinterpret_cast<const float4*>(A);

    if (MODE == 0) {
        const float4* B4 = reinterpret_cast<const float4*>(B);
        #pragma unroll
        for (int j = 0; j < 8; j++) {
            int r = rg + j * 8;
            int row = row0 + r;
            float4 v = make_float4(0.f, 0.f, 0.f, 0.f);
            if (row < N_NODES) {
                float4 a = A4[(size_t)row * D4 + cg];
                float4 b = B4[(size_t)row * D4 + cg];
                v = make_float4(a.x + b.x, a.y + b.y, a.z + b.z, a.w + b.w);
            }
            Rl[r][cg] = v;
        }
    } else {
        float4 sc, sh;
        bn_coef4(st_in, st_in + 128, bn_g, bn_b, cg, sc, sh);
        #pragma unroll
        for (int j = 0; j < 8; j++) {
            int r = rg + j * 8;
            int row = row0 + r;
            float4 v = make_float4(0.f, 0.f, 0.f, 0.f);
            if (row < N_NODES) {
                float4 a = A4[(size_t)row * D4 + cg];
                v.x = fmaxf(fmaf(a.x, sc.x, sh.x), 0.f);
                v.y = fmaxf(fmaf(a.y, sc.y, sh.y), 0.f);
                v.z = fmaxf(fmaf(a.z, sc.z, sh.z), 0.f);
                v.w = fmaxf(fmaf(a.w, sc.w, sh.w), 0.f);
            }
            Rl[r][cg] = v;
        }
    }
    __syncthreads();

    const float4* W4 = reinterpret_cast<const float4*>(W);
    float4 bv = reinterpret_cast<const float4*>(bias)[cg];
    float4 acc[8];
    #pragma unroll
    for (int i = 0; i < 8; i++) acc[i] = bv;

    for (int k = 0; k < DIM; k += 4) {
        float4 w0 = W4[(k + 0) * D4 + cg];
        float4 w1 = W4[(k + 1) * D4 + cg];
        float4 w2 = W4[(k + 2) * D4 + cg];
        float4 w3 = W4[(k + 3) * D4 + cg];
        #pragma unroll
        for (int i = 0; i < 8; i++) {
            float4 rv = Rl[rg * 8 + i][k >> 2];
            acc[i] = f4fma(rv.x, w0, acc[i]);
            acc[i] = f4fma(rv.y, w1, acc[i]);
            acc[i] = f4fma(rv.z, w2, acc[i]);
            acc[i] = f4fma(rv.w, w3, acc[i]);
        }
    }

    float4* out4 = reinterpret_cast<float4*>(out);
    #pragma unroll
    for (int i = 0; i < 8; i++) {
        int row = row0 + rg * 8 + i;
        if (row < N_NODES) out4[(size_t)row * D4 + cg] = acc[i];
    }

    float4 psum = make_float4(0.f, 0.f, 0.f, 0.f);
    float4 psq  = make_float4(0.f, 0.f, 0.f, 0.f);
    #pragma unroll
    for (int i = 0; i < 8; i++) {
        int row = row0 + rg * 8 + i;
        if (row < N_NODES) {
            psum.x += acc[i].x; psum.y += acc[i].y; psum.z += acc[i].z; psum.w += acc[i].w;
            psq.x += acc[i].x * acc[i].x; psq.y += acc[i].y * acc[i].y;
            psq.z += acc[i].z * acc[i].z; psq.w += acc[i].w * acc[i].w;
        }
    }
    __syncthreads();
    float4* red = &Rl[0][0];
    red[t]       = psum;
    red[256 + t] = psq;
    __syncthreads();
    if (t < 32) {
        float4 s = make_float4(0.f, 0.f, 0.f, 0.f);
        float4 q = make_float4(0.f, 0.f, 0.f, 0.f);
        #pragma unroll
        for (int r = 0; r < 8; r++) {
            float4 a = red[r * 32 + t];
            float4 b = red[256 + r * 32 + t];
            s.x += a.x; s.y += a.y; s.z += a.z; s.w += a.w;
            q.x += b.x; q.y += b.y; q.z += b.z; q.w += b.w;
        }
        float* gs = gsum + t * 4;
        float* gq = gsq + t * 4;
        unsafeAtomicAdd(gs + 0, s.x); unsafeAtomicAdd(gs + 1, s.y);
        unsafeAtomicAdd(gs + 2, s.z); unsafeAtomicAdd(gs + 3, s.w);
        unsafeAtomicAdd(gq + 0, q.x); unsafeAtomicAdd(gq + 1, q.y);
        unsafeAtomicAdd(gq + 2, q.z); unsafeAtomicAdd(gq + 3, q.w);
    }
}

// ---------------- y = relu(BN(x; stI)), accumulate column stats of y ----------------
__global__ __launch_bounds__(256) void bn_apply_stats_kernel(
    const float* __restrict__ x, const float* __restrict__ st_in,
    const float* __restrict__ bn_g, const float* __restrict__ bn_b,
    float* __restrict__ y, float* __restrict__ gsum, float* __restrict__ gsq)
{
    const int t = threadIdx.x;
    const int cg = t & 31;
    float4 sc, sh;
    bn_coef4(st_in, st_in + 128, bn_g, bn_b, cg, sc, sh);
    const float4* x4 = reinterpret_cast<const float4*>(x);
    float4* y4 = reinterpret_cast<float4*>(y);
    float4 psum = make_float4(0.f, 0.f, 0.f, 0.f);
    float4 psq  = make_float4(0.f, 0.f, 0.f, 0.f);
    const int total = N_NODES * D4;
    const int stride = gridDim.x * 256;
    for (int idx = blockIdx.x * 256 + t; idx < total; idx += stride) {
        float4 v = x4[idx];
        v.x = fmaxf(fmaf(v.x, sc.x, sh.x), 0.f);
        v.y = fmaxf(fmaf(v.y, sc.y, sh.y), 0.f);
        v.z = fmaxf(fmaf(v.z, sc.z, sh.z), 0.f);
        v.w = fmaxf(fmaf(v.w, sc.w, sh.w), 0.f);
        y4[idx] = v;
        psum.x += v.x; psum.y += v.y; psum.z += v.z; psum.w += v.w;
        psq.x += v.x * v.x; psq.y += v.y * v.y; psq.z += v.z * v.z; psq.w += v.w * v.w;
    }
    __shared__ float4 red[512];
    red[t]       = psum;
    red[256 + t] = psq;
    __syncthreads();
    if (t < 32) {
        float4 s = make_float4(0.f, 0.f, 0.f, 0.f);
        float4 q = make_float4(0.f, 0.f, 0.f, 0.f);
        #pragma unroll
        for (int r = 0; r < 8; r++) {
            float4 a = red[r * 32 + t];
            float4 b = red[256 + r * 32 + t];
            s.x += a.x; s.y += a.y; s.z += a.z; s.w += a.w;
            q.x += b.x; q.y += b.y; q.z += b.z; q.w += b.w;
        }
        float* gs = gsum + t * 4;
        float* gq = gsq + t * 4;
        unsafeAtomicAdd(gs + 0, s.x); unsafeAtomicAdd(gs + 1, s.y);
        unsafeAtomicAdd(gs + 2, s.z); unsafeAtomicAdd(gs + 3, s.w);
        unsafeAtomicAdd(gq + 0, q.x); unsafeAtomicAdd(gq + 1, q.y);
        unsafeAtomicAdd(gq + 2, q.z); unsafeAtomicAdd(gq + 3, q.w);
    }
}

// ---------------- y = relu(BN(x; stI)) ----------------
__global__ __launch_bounds__(256) void bn_apply_kernel(
    const float* __restrict__ x, const float* __restrict__ st_in,
    const float* __restrict__ bn_g, const float* __restrict__ bn_b,
    float* __restrict__ y)
{
    const int t = threadIdx.x;
    const int cg = t & 31;
    float4 sc, sh;
    bn_coef4(st_in, st_in + 128, bn_g, bn_b, cg, sc, sh);
    const float4* x4 = reinterpret_cast<const float4*>(x);
    float4* y4 = reinterpret_cast<float4*>(y);
    const int total = N_NODES * D4;
    const int stride = gridDim.x * 256;
    for (int idx = blockIdx.x * 256 + t; idx < total; idx += stride) {
        float4 v = x4[idx];
        v.x = fmaxf(fmaf(v.x, sc.x, sh.x), 0.f);
        v.y = fmaxf(fmaf(v.y, sc.y, sh.y), 0.f);
        v.z = fmaxf(fmaf(v.z, sc.z, sh.z), 0.f);
        v.w = fmaxf(fmaf(v.w, sc.w, sh.w), 0.f);
        y4[idx] = v;
    }
}

extern "C" void kernel_launch(void* const* d_in, const int* in_sizes, int n_in,
                              void* d_out, int out_size, void* d_ws, size_t ws_size,
                              hipStream_t stream)
{
    const float* h0    = (const float*)d_in[0];
    const int*   src   = (const int*)d_in[1];
    const int*   dst   = (const int*)d_in[2];
    const float* ew    = (const float*)d_in[3];
    const float* W1    = (const float*)d_in[4];
    const float* b1    = (const float*)d_in[5];
    const float* bn1_g = (const float*)d_in[6];
    const float* bn1_b = (const float*)d_in[7];
    const float* W2    = (const float*)d_in[8];
    const float* b2    = (const float*)d_in[9];
    const float* bna_g = (const float*)d_in[10];
    const float* bna_b = (const float*)d_in[11];
    const float* bno_g = (const float*)d_in[12];
    const float* bno_b = (const float*)d_in[13];

    float* agg    = (float*)d_ws;                         // N*D (also reused as x2)
    float* xbuf   = agg + (size_t)N_NODES * DIM;          // N*D (x1, then x_a)
    float* stats  = xbuf + (size_t)N_NODES * DIM;         // 9 * 512 floats
    int*   counts = (int*)(stats + 9 * 512);              // N ints
    int*   offs   = counts + N_NODES;                     // N+1 ints
    int*   cursor = offs + N_NODES + 1;                   // N ints
    int*   bsum   = cursor + N_NODES;                     // 196
    int*   bscan  = bsum + NBLK_SCAN;                     // 196
    int2*  eperm  = (int2*)(((uintptr_t)(bscan + NBLK_SCAN) + 15) & ~(uintptr_t)15); // E int2
    float* hout   = (float*)d_out;

    hipMemsetAsync(stats, 0, 9 * 512 * sizeof(float), stream);

    const int gemm_grid = (N_NODES + 63) / 64;            // 782
    const int edge_grid = (N_EDGES + 255) / 256;          // 3125
    const int agg_grid  = (N_NODES * 32 + 255) / 256;     // 6250

    for (int i = 0; i < N_LAYERS; i++) {
        const float* hin = (i == 0) ? h0 : hout;
        const int* srcL = src + (size_t)i * N_EDGES;
        const int* dstL = dst + (size_t)i * N_EDGES;
        const float* ewL = ew + (size_t)i * N_EDGES;
        float* st1 = stats + (i * 3 + 0) * 512;  // [sum | sumsq]
        float* stA = stats + (i * 3 + 1) * 512;
        float* stO = stats + (i * 3 + 2) * 512;

        // --- CSR build + gather aggregation (no float atomics) ---
        hipMemsetAsync(counts, 0, N_NODES * sizeof(int), stream);
        hist_kernel<<<edge_grid, 256, 0, stream>>>(dstL, counts);
        partial_kernel<<<NBLK_SCAN, 256, 0, stream>>>(counts, bsum);
        scan_small_kernel<<<1, 256, 0, stream>>>(bsum, bscan, offs);
        write_offs_kernel<<<NBLK_SCAN, 256, 0, stream>>>(counts, bscan, offs, cursor);
        fill_kernel<<<edge_grid, 256, 0, stream>>>(srcL, dstL, ewL, cursor, eperm);
        agg_kernel<<<agg_grid, 256, 0, stream>>>(hin, offs, eperm, agg);

        gemm_kernel<0><<<gemm_grid, 256, 0, stream>>>(
            hin, agg, nullptr, nullptr, nullptr,
            W1 + (size_t)i * DIM * DIM, b1 + (size_t)i * DIM,
            xbuf, st1, st1 + 128);

        gemm_kernel<1><<<gemm_grid, 256, 0, stream>>>(
            xbuf, nullptr, st1, bn1_g + (size_t)i * DIM, bn1_b + (size_t)i * DIM,
            W2 + (size_t)i * DIM * DIM, b2 + (size_t)i * DIM,
            agg, stA, stA + 128);

        bn_apply_stats_kernel<<<1024, 256, 0, stream>>>(
            agg, stA, bna_g + (size_t)i * DIM, bna_b + (size_t)i * DIM,
            xbuf, stO, stO + 128);

        bn_apply_kernel<<<1024, 256, 0, stream>>>(
            xbuf, stO, bno_g + (size_t)i * DIM, bno_b + (size_t)i * DIM, hout);
    }
}

// Round 5
// 1161.637 us; speedup vs baseline: 4.3795x; 1.3285x over previous
//
#include <hip/hip_runtime.h>

#define N_NODES 50000
#define DIM 128
#define D4 32            // DIM/4
#define N_EDGES 800000
#define N_LAYERS 3
#define BN_EPS 1e-5f
#define NBLK_SCAN ((N_NODES + 255) / 256)   // 196

typedef __attribute__((ext_vector_type(8))) short bf16x8;
typedef __attribute__((ext_vector_type(4))) float f32x4;

__device__ __forceinline__ float4 f4fma(float a, const float4& b, const float4& c) {
    return make_float4(fmaf(a, b.x, c.x), fmaf(a, b.y, c.y),
                       fmaf(a, b.z, c.z), fmaf(a, b.w, c.w));
}

// fp32 -> bf16 round-to-nearest-even
__device__ __forceinline__ unsigned short f2bf(float f) {
    unsigned int u = __float_as_uint(f);
    u = (u + 0x7FFFu + ((u >> 16) & 1u)) >> 16;
    return (unsigned short)u;
}

// scale/shift from raw BN stats
__device__ __forceinline__ void bn_coef(float sum, float sq, float g, float b,
                                        float& sc, float& sh) {
    float mean = sum * (1.f / N_NODES);
    float var  = sq * (1.f / N_NODES) - mean * mean;
    float rstd = rsqrtf(var + BN_EPS);
    sc = g * rstd;
    sh = b - mean * sc;
}

__device__ __forceinline__ void bn_coef4(const float* gsum, const float* gsq,
                                         const float* g, const float* b, int cg,
                                         float4& sc, float4& sh) {
    float4 s  = reinterpret_cast<const float4*>(gsum)[cg];
    float4 q  = reinterpret_cast<const float4*>(gsq)[cg];
    float4 gg = reinterpret_cast<const float4*>(g)[cg];
    float4 bb = reinterpret_cast<const float4*>(b)[cg];
    bn_coef(s.x, q.x, gg.x, bb.x, sc.x, sh.x);
    bn_coef(s.y, q.y, gg.y, bb.y, sc.y, sh.y);
    bn_coef(s.z, q.z, gg.z, bb.z, sc.z, sh.z);
    bn_coef(s.w, q.w, gg.w, bb.w, sc.w, sh.w);
}

// ---------------- W transpose + bf16 convert (once per launch, all 6 weights) ----
// wtg[m][c][k] = bf16(W_m[k][c]),  m in 0..5  (W1_0..2 then W2_0..2)
__global__ __launch_bounds__(256) void wt_kernel(
    const float* __restrict__ W1, const float* __restrict__ W2,
    unsigned short* __restrict__ wtg)
{
    int tid = blockIdx.x * 256 + threadIdx.x;          // 6*16384 total
    if (tid >= 6 * DIM * DIM) return;
    int m = tid >> 14;           // /16384
    int r = tid & 16383;
    int c = r >> 7;              // output row (col of W)
    int k = r & 127;             // output col (row of W)
    const float* src = (m < 3) ? (W1 + (size_t)m * DIM * DIM)
                               : (W2 + (size_t)(m - 3) * DIM * DIM);
    wtg[tid] = f2bf(src[k * DIM + c]);
}

// ---------------- CSR build: histogram of dst ----------------
__global__ __launch_bounds__(256) void hist_kernel(
    const int* __restrict__ dst, int* __restrict__ counts)
{
    int e = blockIdx.x * 256 + threadIdx.x;
    if (e < N_EDGES) atomicAdd(&counts[dst[e]], 1);
}

// ---------------- scan stage 1: per-256-chunk sums ----------------
__global__ __launch_bounds__(256) void partial_kernel(
    const int* __restrict__ counts, int* __restrict__ bsum)
{
    __shared__ int s[256];
    int idx = blockIdx.x * 256 + threadIdx.x;
    int v = (idx < N_NODES) ? counts[idx] : 0;
    s[threadIdx.x] = v;
    __syncthreads();
    #pragma unroll
    for (int off = 128; off > 0; off >>= 1) {
        if (threadIdx.x < off) s[threadIdx.x] += s[threadIdx.x + off];
        __syncthreads();
    }
    if (threadIdx.x == 0) bsum[blockIdx.x] = s[0];
}

// ---------------- scan stage 2: scan the 196 block sums ----------------
__global__ __launch_bounds__(256) void scan_small_kernel(
    const int* __restrict__ bsum, int* __restrict__ bscan, int* __restrict__ offsets)
{
    __shared__ int s[256];
    int t = threadIdx.x;
    int v = (t < NBLK_SCAN) ? bsum[t] : 0;
    s[t] = v;
    __syncthreads();
    #pragma unroll
    for (int off = 1; off < 256; off <<= 1) {
        int u = (t >= off) ? s[t - off] : 0;
        __syncthreads();
        s[t] += u;
        __syncthreads();
    }
    if (t < NBLK_SCAN) bscan[t] = s[t] - v;     // exclusive
    if (t == 255) offsets[N_NODES] = s[255];    // total (= N_EDGES)
}

// ---------------- scan stage 3: per-chunk exclusive scan + base ----------------
__global__ __launch_bounds__(256) void write_offs_kernel(
    const int* __restrict__ counts, const int* __restrict__ bscan,
    int* __restrict__ offsets, int* __restrict__ cursor)
{
    __shared__ int s[256];
    int t = threadIdx.x;
    int idx = blockIdx.x * 256 + t;
    int v = (idx < N_NODES) ? counts[idx] : 0;
    s[t] = v;
    __syncthreads();
    #pragma unroll
    for (int off = 1; off < 256; off <<= 1) {
        int u = (t >= off) ? s[t - off] : 0;
        __syncthreads();
        s[t] += u;
        __syncthreads();
    }
    int ex = s[t] - v + bscan[blockIdx.x];
    if (idx < N_NODES) { offsets[idx] = ex; cursor[idx] = ex; }
}

// ---------------- CSR build: fill permuted (src, weight) ----------------
__global__ __launch_bounds__(256) void fill_kernel(
    const int* __restrict__ src, const int* __restrict__ dst,
    const float* __restrict__ ew, int* __restrict__ cursor,
    int2* __restrict__ eperm)
{
    int e = blockIdx.x * 256 + threadIdx.x;
    if (e >= N_EDGES) return;
    int pos = atomicAdd(&cursor[dst[e]], 1);
    eperm[pos] = make_int2(src[e], __float_as_int(ew[e]));
}

// ---------------- aggregate: agg[n] = sum_{e: dst=n} w_e * h[src_e] ----------------
__global__ __launch_bounds__(256) void agg_kernel(
    const float* __restrict__ h, const int* __restrict__ offsets,
    const int2* __restrict__ eperm, float* __restrict__ agg)
{
    int gid = blockIdx.x * 256 + threadIdx.x;
    int node = gid >> 5;
    if (node >= N_NODES) return;
    int lane = gid & 31;
    int beg = offsets[node], end = offsets[node + 1];
    const float4* h4 = reinterpret_cast<const float4*>(h);
    float4 v = make_float4(0.f, 0.f, 0.f, 0.f);
    for (int j = beg; j < end; j++) {
        int2 e = eperm[j];
        float w = __int_as_float(e.y);
        float4 x = h4[(size_t)e.x * D4 + lane];
        v = f4fma(w, x, v);
    }
    reinterpret_cast<float4*>(agg)[(size_t)node * D4 + lane] = v;
}

// ---------------- MFMA GEMM: out = f(in) @ W + bias, + column stats ----------------
// MODE 0: in = A + B                 (GEMM1: r = h + agg)
// MODE 1: in = relu(BN(A; st,g,b))   (GEMM2: BN1+ReLU fused on staging)
// 64x128 tile per block, 4 waves, bf16 MFMA 16x16x32, fp32 accum.
template<int MODE>
__global__ __launch_bounds__(256) void gemm_kernel(
    const float* __restrict__ A, const float* __restrict__ B,
    const float* __restrict__ st_in, const float* __restrict__ bn_g,
    const float* __restrict__ bn_b,
    const unsigned short* __restrict__ Wt, const float* __restrict__ bias,
    float* __restrict__ out, float* __restrict__ gsum, float* __restrict__ gsq)
{
    __shared__ unsigned short A_sm[64 * DIM];    // 16 KB bf16, XOR-swizzled
    __shared__ unsigned short W_sm[DIM * DIM];   // 32 KB bf16 W^T, XOR-swizzled
    __shared__ float2 scsh[DIM];                 // BN coefs (MODE 1)

    const int t = threadIdx.x;
    const int row0 = blockIdx.x * 64;

    if (MODE == 1) {
        if (t < 128) {
            float sc, sh;
            bn_coef(st_in[t], st_in[128 + t], bn_g[t], bn_b[t], sc, sh);
            scsh[t] = make_float2(sc, sh);
        }
        __syncthreads();
    }

    // ---- stage W^T (already bf16, c-major): 2048 16B chunks ----
    {
        const uint4* wsrc = reinterpret_cast<const uint4*>(Wt);
        #pragma unroll
        for (int j = 0; j < 8; j++) {
            int id = t + j * 256;            // 0..2047
            int c  = id >> 4;
            int kc = id & 15;
            int sidx = (c * DIM + kc * 8) ^ ((c & 7) << 3);
            *reinterpret_cast<uint4*>(&W_sm[sidx]) = wsrc[id];
        }
    }

    // ---- stage A tile -> bf16 (swizzled) ----
    {
        const float4* A4 = reinterpret_cast<const float4*>(A);
        const float4* B4 = reinterpret_cast<const float4*>(B);
        #pragma unroll
        for (int j = 0; j < 8; j++) {
            int id = t + j * 256;            // 0..2047
            int r  = id >> 5;                // tile row 0..63
            int q  = id & 31;                // float4 col group
            int row = row0 + r;
            float4 v = make_float4(0.f, 0.f, 0.f, 0.f);
            if (row < N_NODES) {
                float4 a = A4[(size_t)row * D4 + q];
                if (MODE == 0) {
                    float4 b = B4[(size_t)row * D4 + q];
                    v = make_float4(a.x + b.x, a.y + b.y, a.z + b.z, a.w + b.w);
                } else {
                    float2 c0 = scsh[q * 4 + 0], c1 = scsh[q * 4 + 1];
                    float2 c2 = scsh[q * 4 + 2], c3 = scsh[q * 4 + 3];
                    v.x = fmaxf(fmaf(a.x, c0.x, c0.y), 0.f);
                    v.y = fmaxf(fmaf(a.y, c1.x, c1.y), 0.f);
                    v.z = fmaxf(fmaf(a.z, c2.x, c2.y), 0.f);
                    v.w = fmaxf(fmaf(a.w, c3.x, c3.y), 0.f);
                }
            }
            ushort4 u = make_ushort4(f2bf(v.x), f2bf(v.y), f2bf(v.z), f2bf(v.w));
            int sidx = (r * DIM + q * 4) ^ ((r & 7) << 3);
            *reinterpret_cast<ushort4*>(&A_sm[sidx]) = u;
        }
    }
    __syncthreads();

    // ---- MFMA: wave w owns rows w*16..w*16+15, all 8 col-blocks ----
    const int w    = t >> 6;
    const int lane = t & 63;
    const int lrow = lane & 15;
    const int lkg  = lane >> 4;
    const int arow = w * 16 + lrow;

    bf16x8 afr[4];
    #pragma unroll
    for (int ks = 0; ks < 4; ks++) {
        int k = ks * 32 + lkg * 8;
        int idx = (arow * DIM + k) ^ ((arow & 7) << 3);
        afr[ks] = *reinterpret_cast<const bf16x8*>(&A_sm[idx]);
    }

    f32x4 acc[8];
    #pragma unroll
    for (int cb = 0; cb < 8; cb++) {
        f32x4 a = {0.f, 0.f, 0.f, 0.f};
        int col = cb * 16 + lrow;
        #pragma unroll
        for (int ks = 0; ks < 4; ks++) {
            int k = ks * 32 + lkg * 8;
            int widx = (col * DIM + k) ^ ((col & 7) << 3);
            bf16x8 bfr = *reinterpret_cast<const bf16x8*>(&W_sm[widx]);
            a = __builtin_amdgcn_mfma_f32_16x16x32_bf16(afr[ks], bfr, a, 0, 0, 0);
        }
        acc[cb] = a;
    }

    // ---- epilogue: bias add, store, column stats ----
    float s_c[8], q_c[8];
    #pragma unroll
    for (int cb = 0; cb < 8; cb++) {
        int col = cb * 16 + lrow;
        float bc = bias[col];
        float s = 0.f, q = 0.f;
        #pragma unroll
        for (int r = 0; r < 4; r++) {
            int row = row0 + w * 16 + lkg * 4 + r;
            if (row < N_NODES) {
                float v = acc[cb][r] + bc;
                out[(size_t)row * DIM + col] = v;
                s += v; q += v * v;
            }
        }
        s_c[cb] = s; q_c[cb] = q;
    }
    #pragma unroll
    for (int cb = 0; cb < 8; cb++) {
        s_c[cb] += __shfl_xor(s_c[cb], 16); s_c[cb] += __shfl_xor(s_c[cb], 32);
        q_c[cb] += __shfl_xor(q_c[cb], 16); q_c[cb] += __shfl_xor(q_c[cb], 32);
    }
    __syncthreads();                 // done with A_sm, reuse as reduce scratch
    float* red = reinterpret_cast<float*>(A_sm);   // [4 waves][2][128]
    if (lkg == 0) {
        #pragma unroll
        for (int cb = 0; cb < 8; cb++) {
            red[w * 256 + cb * 16 + lrow]       = s_c[cb];
            red[w * 256 + 128 + cb * 16 + lrow] = q_c[cb];
        }
    }
    __syncthreads();
    if (t < 128) {
        float s = red[t] + red[256 + t] + red[512 + t] + red[768 + t];
        unsafeAtomicAdd(&gsum[t], s);
    } else if (t < 256) {
        int c = t - 128;
        float q = red[128 + c] + red[384 + c] + red[640 + c] + red[896 + c];
        unsafeAtomicAdd(&gsq[c], q);
    }
}

// ---------------- stats of xa = relu(BN(x; stA)) — no data write ----------------
__global__ __launch_bounds__(256) void bn_stats_kernel(
    const float* __restrict__ x, const float* __restrict__ st_in,
    const float* __restrict__ bn_g, const float* __restrict__ bn_b,
    float* __restrict__ gsum, float* __restrict__ gsq)
{
    const int t = threadIdx.x;
    const int cg = t & 31;
    float4 sc, sh;
    bn_coef4(st_in, st_in + 128, bn_g, bn_b, cg, sc, sh);
    const float4* x4 = reinterpret_cast<const float4*>(x);
    float4 psum = make_float4(0.f, 0.f, 0.f, 0.f);
    float4 psq  = make_float4(0.f, 0.f, 0.f, 0.f);
    const int total = N_NODES * D4;
    const int stride = gridDim.x * 256;
    for (int idx = blockIdx.x * 256 + t; idx < total; idx += stride) {
        float4 v = x4[idx];
        v.x = fmaxf(fmaf(v.x, sc.x, sh.x), 0.f);
        v.y = fmaxf(fmaf(v.y, sc.y, sh.y), 0.f);
        v.z = fmaxf(fmaf(v.z, sc.z, sh.z), 0.f);
        v.w = fmaxf(fmaf(v.w, sc.w, sh.w), 0.f);
        psum.x += v.x; psum.y += v.y; psum.z += v.z; psum.w += v.w;
        psq.x += v.x * v.x; psq.y += v.y * v.y; psq.z += v.z * v.z; psq.w += v.w * v.w;
    }
    __shared__ float4 red[512];
    red[t]       = psum;
    red[256 + t] = psq;
    __syncthreads();
    if (t < 32) {
        float4 s = make_float4(0.f, 0.f, 0.f, 0.f);
        float4 q = make_float4(0.f, 0.f, 0.f, 0.f);
        #pragma unroll
        for (int r = 0; r < 8; r++) {
            float4 a = red[r * 32 + t];
            float4 b = red[256 + r * 32 + t];
            s.x += a.x; s.y += a.y; s.z += a.z; s.w += a.w;
            q.x += b.x; q.y += b.y; q.z += b.z; q.w += b.w;
        }
        float* gs = gsum + t * 4;
        float* gq = gsq + t * 4;
        unsafeAtomicAdd(gs + 0, s.x); unsafeAtomicAdd(gs + 1, s.y);
        unsafeAtomicAdd(gs + 2, s.z); unsafeAtomicAdd(gs + 3, s.w);
        unsafeAtomicAdd(gq + 0, q.x); unsafeAtomicAdd(gq + 1, q.y);
        unsafeAtomicAdd(gq + 2, q.z); unsafeAtomicAdd(gq + 3, q.w);
    }
}

// ---------------- h = relu(BN_o(relu(BN_a(x)))) ----------------
__global__ __launch_bounds__(256) void bn_final_kernel(
    const float* __restrict__ x,
    const float* __restrict__ stA, const float* __restrict__ ga, const float* __restrict__ ba,
    const float* __restrict__ stO, const float* __restrict__ go, const float* __restrict__ bo,
    float* __restrict__ y)
{
    const int t = threadIdx.x;
    const int cg = t & 31;
    float4 sca, sha, sco, sho;
    bn_coef4(stA, stA + 128, ga, ba, cg, sca, sha);
    bn_coef4(stO, stO + 128, go, bo, cg, sco, sho);
    const float4* x4 = reinterpret_cast<const float4*>(x);
    float4* y4 = reinterpret_cast<float4*>(y);
    const int total = N_NODES * D4;
    const int stride = gridDim.x * 256;
    for (int idx = blockIdx.x * 256 + t; idx < total; idx += stride) {
        float4 v = x4[idx];
        v.x = fmaxf(fmaf(v.x, sca.x, sha.x), 0.f);
        v.y = fmaxf(fmaf(v.y, sca.y, sha.y), 0.f);
        v.z = fmaxf(fmaf(v.z, sca.z, sha.z), 0.f);
        v.w = fmaxf(fmaf(v.w, sca.w, sha.w), 0.f);
        v.x = fmaxf(fmaf(v.x, sco.x, sho.x), 0.f);
        v.y = fmaxf(fmaf(v.y, sco.y, sho.y), 0.f);
        v.z = fmaxf(fmaf(v.z, sco.z, sho.z), 0.f);
        v.w = fmaxf(fmaf(v.w, sco.w, sho.w), 0.f);
        y4[idx] = v;
    }
}

extern "C" void kernel_launch(void* const* d_in, const int* in_sizes, int n_in,
                              void* d_out, int out_size, void* d_ws, size_t ws_size,
                              hipStream_t stream)
{
    const float* h0    = (const float*)d_in[0];
    const int*   src   = (const int*)d_in[1];
    const int*   dst   = (const int*)d_in[2];
    const float* ew    = (const float*)d_in[3];
    const float* W1    = (const float*)d_in[4];
    const float* b1    = (const float*)d_in[5];
    const float* bn1_g = (const float*)d_in[6];
    const float* bn1_b = (const float*)d_in[7];
    const float* W2    = (const float*)d_in[8];
    const float* b2    = (const float*)d_in[9];
    const float* bna_g = (const float*)d_in[10];
    const float* bna_b = (const float*)d_in[11];
    const float* bno_g = (const float*)d_in[12];
    const float* bno_b = (const float*)d_in[13];

    float* agg    = (float*)d_ws;                         // N*D (also reused as x2)
    float* xbuf   = agg + (size_t)N_NODES * DIM;          // N*D (x1)
    float* stats  = xbuf + (size_t)N_NODES * DIM;         // 9 * 512 floats
    int*   counts = (int*)(stats + 9 * 512);              // N ints
    int*   offs   = counts + N_NODES;                     // N+1 ints
    int*   cursor = offs + N_NODES + 1;                   // N ints
    int*   bsum   = cursor + N_NODES;                     // 196
    int*   bscan  = bsum + NBLK_SCAN;                     // 196
    int2*  eperm  = (int2*)(((uintptr_t)(bscan + NBLK_SCAN) + 15) & ~(uintptr_t)15); // E int2
    unsigned short* wtg = (unsigned short*)(eperm + N_EDGES);  // 6*128*128 bf16
    float* hout   = (float*)d_out;

    hipMemsetAsync(stats, 0, 9 * 512 * sizeof(float), stream);
    wt_kernel<<<(6 * DIM * DIM + 255) / 256, 256, 0, stream>>>(W1, W2, wtg);

    const int gemm_grid = (N_NODES + 63) / 64;            // 782
    const int edge_grid = (N_EDGES + 255) / 256;          // 3125
    const int agg_grid  = (N_NODES * 32 + 255) / 256;     // 6250

    for (int i = 0; i < N_LAYERS; i++) {
        const float* hin = (i == 0) ? h0 : hout;
        const int* srcL = src + (size_t)i * N_EDGES;
        const int* dstL = dst + (size_t)i * N_EDGES;
        const float* ewL = ew + (size_t)i * N_EDGES;
        float* st1 = stats + (i * 3 + 0) * 512;  // [sum | sumsq]
        float* stA = stats + (i * 3 + 1) * 512;
        float* stO = stats + (i * 3 + 2) * 512;
        const unsigned short* wt1 = wtg + (size_t)i * DIM * DIM;
        const unsigned short* wt2 = wtg + (size_t)(i + 3) * DIM * DIM;

        // --- CSR build + gather aggregation (no float atomics) ---
        hipMemsetAsync(counts, 0, N_NODES * sizeof(int), stream);
        hist_kernel<<<edge_grid, 256, 0, stream>>>(dstL, counts);
        partial_kernel<<<NBLK_SCAN, 256, 0, stream>>>(counts, bsum);
        scan_small_kernel<<<1, 256, 0, stream>>>(bsum, bscan, offs);
        write_offs_kernel<<<NBLK_SCAN, 256, 0, stream>>>(counts, bscan, offs, cursor);
        fill_kernel<<<edge_grid, 256, 0, stream>>>(srcL, dstL, ewL, cursor, eperm);
        agg_kernel<<<agg_grid, 256, 0, stream>>>(hin, offs, eperm, agg);

        gemm_kernel<0><<<gemm_grid, 256, 0, stream>>>(
            hin, agg, nullptr, nullptr, nullptr,
            wt1, b1 + (size_t)i * DIM, xbuf, st1, st1 + 128);

        gemm_kernel<1><<<gemm_grid, 256, 0, stream>>>(
            xbuf, nullptr, st1, bn1_g + (size_t)i * DIM, bn1_b + (size_t)i * DIM,
            wt2, b2 + (size_t)i * DIM, agg, stA, stA + 128);

        bn_stats_kernel<<<1024, 256, 0, stream>>>(
            agg, stA, bna_g + (size_t)i * DIM, bna_b + (size_t)i * DIM,
            stO, stO + 128);

        bn_final_kernel<<<1024, 256, 0, stream>>>(
            agg, stA, bna_g + (size_t)i * DIM, bna_b + (size_t)i * DIM,
            stO, bno_g + (size_t)i * DIM, bno_b + (size_t)i * DIM, hout);
    }
}

// Round 6
// 809.139 us; speedup vs baseline: 6.2874x; 1.4356x over previous
//
#include <hip/hip_runtime.h>

#define N_NODES 50000
#define DIM 128
#define D4 32            // DIM/4
#define N_EDGES 800000
#define N_LAYERS 3
#define BN_EPS 1e-5f
#define NBLK_SCAN ((N_NODES + 255) / 256)   // 196
#define NREP 16                              // stat replicas (atomic-chain breaker)
#define STSZ (256 * NREP)                    // floats per stat set

typedef __attribute__((ext_vector_type(8))) short bf16x8;
typedef __attribute__((ext_vector_type(4))) float f32x4;

__device__ __forceinline__ float4 f4fma(float a, const float4& b, const float4& c) {
    return make_float4(fmaf(a, b.x, c.x), fmaf(a, b.y, c.y),
                       fmaf(a, b.z, c.z), fmaf(a, b.w, c.w));
}

// fp32 -> bf16 round-to-nearest-even
__device__ __forceinline__ unsigned short f2bf(float f) {
    unsigned int u = __float_as_uint(f);
    u = (u + 0x7FFFu + ((u >> 16) & 1u)) >> 16;
    return (unsigned short)u;
}

// scale/shift from raw BN stats
__device__ __forceinline__ void bn_coef(float sum, float sq, float g, float b,
                                        float& sc, float& sh) {
    float mean = sum * (1.f / N_NODES);
    float var  = sq * (1.f / N_NODES) - mean * mean;
    float rstd = rsqrtf(var + BN_EPS);
    sc = g * rstd;
    sh = b - mean * sc;
}

// sum NREP replicas, then coefs (vector form; cg = float4 column group)
__device__ __forceinline__ void bn_coef4(const float* st,
                                         const float* g, const float* b, int cg,
                                         float4& sc, float4& sh) {
    float4 s = make_float4(0.f, 0.f, 0.f, 0.f);
    float4 q = make_float4(0.f, 0.f, 0.f, 0.f);
    #pragma unroll
    for (int r = 0; r < NREP; r++) {
        const float4* p = reinterpret_cast<const float4*>(st + r * 256);
        float4 a = p[cg];          // sum part
        float4 c = p[32 + cg];     // sq part
        s.x += a.x; s.y += a.y; s.z += a.z; s.w += a.w;
        q.x += c.x; q.y += c.y; q.z += c.z; q.w += c.w;
    }
    float4 gg = reinterpret_cast<const float4*>(g)[cg];
    float4 bb = reinterpret_cast<const float4*>(b)[cg];
    bn_coef(s.x, q.x, gg.x, bb.x, sc.x, sh.x);
    bn_coef(s.y, q.y, gg.y, bb.y, sc.y, sh.y);
    bn_coef(s.z, q.z, gg.z, bb.z, sc.z, sh.z);
    bn_coef(s.w, q.w, gg.w, bb.w, sc.w, sh.w);
}

// ---------------- W transpose + bf16 convert (once per launch, all 6 weights) ----
__global__ __launch_bounds__(256) void wt_kernel(
    const float* __restrict__ W1, const float* __restrict__ W2,
    unsigned short* __restrict__ wtg)
{
    int tid = blockIdx.x * 256 + threadIdx.x;          // 6*16384 total
    if (tid >= 6 * DIM * DIM) return;
    int m = tid >> 14;           // /16384
    int r = tid & 16383;
    int c = r >> 7;              // output row (col of W)
    int k = r & 127;             // output col (row of W)
    const float* src = (m < 3) ? (W1 + (size_t)m * DIM * DIM)
                               : (W2 + (size_t)(m - 3) * DIM * DIM);
    wtg[tid] = f2bf(src[k * DIM + c]);
}

// ---------------- CSR build: histogram of dst ----------------
__global__ __launch_bounds__(256) void hist_kernel(
    const int* __restrict__ dst, int* __restrict__ counts)
{
    int e = blockIdx.x * 256 + threadIdx.x;
    if (e < N_EDGES) atomicAdd(&counts[dst[e]], 1);
}

// ---------------- scan stage 1: per-256-chunk sums ----------------
__global__ __launch_bounds__(256) void partial_kernel(
    const int* __restrict__ counts, int* __restrict__ bsum)
{
    __shared__ int s[256];
    int idx = blockIdx.x * 256 + threadIdx.x;
    int v = (idx < N_NODES) ? counts[idx] : 0;
    s[threadIdx.x] = v;
    __syncthreads();
    #pragma unroll
    for (int off = 128; off > 0; off >>= 1) {
        if (threadIdx.x < off) s[threadIdx.x] += s[threadIdx.x + off];
        __syncthreads();
    }
    if (threadIdx.x == 0) bsum[blockIdx.x] = s[0];
}

// ---------------- scan stage 2: scan the 196 block sums ----------------
__global__ __launch_bounds__(256) void scan_small_kernel(
    const int* __restrict__ bsum, int* __restrict__ bscan, int* __restrict__ offsets)
{
    __shared__ int s[256];
    int t = threadIdx.x;
    int v = (t < NBLK_SCAN) ? bsum[t] : 0;
    s[t] = v;
    __syncthreads();
    #pragma unroll
    for (int off = 1; off < 256; off <<= 1) {
        int u = (t >= off) ? s[t - off] : 0;
        __syncthreads();
        s[t] += u;
        __syncthreads();
    }
    if (t < NBLK_SCAN) bscan[t] = s[t] - v;     // exclusive
    if (t == 255) offsets[N_NODES] = s[255];    // total (= N_EDGES)
}

// ---------------- scan stage 3: per-chunk exclusive scan + base ----------------
__global__ __launch_bounds__(256) void write_offs_kernel(
    const int* __restrict__ counts, const int* __restrict__ bscan,
    int* __restrict__ offsets, int* __restrict__ cursor)
{
    __shared__ int s[256];
    int t = threadIdx.x;
    int idx = blockIdx.x * 256 + t;
    int v = (idx < N_NODES) ? counts[idx] : 0;
    s[t] = v;
    __syncthreads();
    #pragma unroll
    for (int off = 1; off < 256; off <<= 1) {
        int u = (t >= off) ? s[t - off] : 0;
        __syncthreads();
        s[t] += u;
        __syncthreads();
    }
    int ex = s[t] - v + bscan[blockIdx.x];
    if (idx < N_NODES) { offsets[idx] = ex; cursor[idx] = ex; }
}

// ---------------- CSR build: fill permuted (src, weight) ----------------
__global__ __launch_bounds__(256) void fill_kernel(
    const int* __restrict__ src, const int* __restrict__ dst,
    const float* __restrict__ ew, int* __restrict__ cursor,
    int2* __restrict__ eperm)
{
    int e = blockIdx.x * 256 + threadIdx.x;
    if (e >= N_EDGES) return;
    int pos = atomicAdd(&cursor[dst[e]], 1);
    eperm[pos] = make_int2(src[e], __float_as_int(ew[e]));
}

// ---------------- aggregate: agg[n] = sum_{e: dst=n} w_e * h[src_e] ----------------
__global__ __launch_bounds__(256) void agg_kernel(
    const float* __restrict__ h, const int* __restrict__ offsets,
    const int2* __restrict__ eperm, float* __restrict__ agg)
{
    int gid = blockIdx.x * 256 + threadIdx.x;
    int node = gid >> 5;
    if (node >= N_NODES) return;
    int lane = gid & 31;
    int beg = offsets[node], end = offsets[node + 1];
    const float4* h4 = reinterpret_cast<const float4*>(h);
    float4 v = make_float4(0.f, 0.f, 0.f, 0.f);
    for (int j = beg; j < end; j++) {
        int2 e = eperm[j];
        float w = __int_as_float(e.y);
        float4 x = h4[(size_t)e.x * D4 + lane];
        v = f4fma(w, x, v);
    }
    reinterpret_cast<float4*>(agg)[(size_t)node * D4 + lane] = v;
}

// ---------------- MFMA GEMM: out = f(in) @ W + bias, + column stats ----------------
// MODE 0: in = A + B                 (GEMM1: r = h + agg)
// MODE 1: in = relu(BN(A; st,g,b))   (GEMM2: BN1+ReLU fused on staging)
template<int MODE>
__global__ __launch_bounds__(256) void gemm_kernel(
    const float* __restrict__ A, const float* __restrict__ B,
    const float* __restrict__ st_in, const float* __restrict__ bn_g,
    const float* __restrict__ bn_b,
    const unsigned short* __restrict__ Wt, const float* __restrict__ bias,
    float* __restrict__ out, float* __restrict__ st_out)
{
    __shared__ unsigned short A_sm[64 * DIM];    // 16 KB bf16, XOR-swizzled
    __shared__ unsigned short W_sm[DIM * DIM];   // 32 KB bf16 W^T, XOR-swizzled
    __shared__ float2 scsh[DIM];                 // BN coefs (MODE 1)

    const int t = threadIdx.x;
    const int row0 = blockIdx.x * 64;

    if (MODE == 1) {
        if (t < 128) {
            float ssum = 0.f, ssq = 0.f;
            #pragma unroll
            for (int r = 0; r < NREP; r++) {
                ssum += st_in[r * 256 + t];
                ssq  += st_in[r * 256 + 128 + t];
            }
            float sc, sh;
            bn_coef(ssum, ssq, bn_g[t], bn_b[t], sc, sh);
            scsh[t] = make_float2(sc, sh);
        }
        __syncthreads();
    }

    // ---- stage W^T (already bf16, c-major): 2048 16B chunks ----
    {
        const uint4* wsrc = reinterpret_cast<const uint4*>(Wt);
        #pragma unroll
        for (int j = 0; j < 8; j++) {
            int id = t + j * 256;            // 0..2047
            int c  = id >> 4;
            int kc = id & 15;
            int sidx = (c * DIM + kc * 8) ^ ((c & 7) << 3);
            *reinterpret_cast<uint4*>(&W_sm[sidx]) = wsrc[id];
        }
    }

    // ---- stage A tile -> bf16 (swizzled) ----
    {
        const float4* A4 = reinterpret_cast<const float4*>(A);
        const float4* B4 = reinterpret_cast<const float4*>(B);
        #pragma unroll
        for (int j = 0; j < 8; j++) {
            int id = t + j * 256;            // 0..2047
            int r  = id >> 5;                // tile row 0..63
            int q  = id & 31;                // float4 col group
            int row = row0 + r;
            float4 v = make_float4(0.f, 0.f, 0.f, 0.f);
            if (row < N_NODES) {
                float4 a = A4[(size_t)row * D4 + q];
                if (MODE == 0) {
                    float4 b = B4[(size_t)row * D4 + q];
                    v = make_float4(a.x + b.x, a.y + b.y, a.z + b.z, a.w + b.w);
                } else {
                    float2 c0 = scsh[q * 4 + 0], c1 = scsh[q * 4 + 1];
                    float2 c2 = scsh[q * 4 + 2], c3 = scsh[q * 4 + 3];
                    v.x = fmaxf(fmaf(a.x, c0.x, c0.y), 0.f);
                    v.y = fmaxf(fmaf(a.y, c1.x, c1.y), 0.f);
                    v.z = fmaxf(fmaf(a.z, c2.x, c2.y), 0.f);
                    v.w = fmaxf(fmaf(a.w, c3.x, c3.y), 0.f);
                }
            }
            ushort4 u = make_ushort4(f2bf(v.x), f2bf(v.y), f2bf(v.z), f2bf(v.w));
            int sidx = (r * DIM + q * 4) ^ ((r & 7) << 3);
            *reinterpret_cast<ushort4*>(&A_sm[sidx]) = u;
        }
    }
    __syncthreads();

    // ---- MFMA: wave w owns rows w*16..w*16+15, all 8 col-blocks ----
    const int w    = t >> 6;
    const int lane = t & 63;
    const int lrow = lane & 15;
    const int lkg  = lane >> 4;
    const int arow = w * 16 + lrow;

    bf16x8 afr[4];
    #pragma unroll
    for (int ks = 0; ks < 4; ks++) {
        int k = ks * 32 + lkg * 8;
        int idx = (arow * DIM + k) ^ ((arow & 7) << 3);
        afr[ks] = *reinterpret_cast<const bf16x8*>(&A_sm[idx]);
    }

    f32x4 acc[8];
    #pragma unroll
    for (int cb = 0; cb < 8; cb++) {
        f32x4 a = {0.f, 0.f, 0.f, 0.f};
        int col = cb * 16 + lrow;
        #pragma unroll
        for (int ks = 0; ks < 4; ks++) {
            int k = ks * 32 + lkg * 8;
            int widx = (col * DIM + k) ^ ((col & 7) << 3);
            bf16x8 bfr = *reinterpret_cast<const bf16x8*>(&W_sm[widx]);
            a = __builtin_amdgcn_mfma_f32_16x16x32_bf16(afr[ks], bfr, a, 0, 0, 0);
        }
        acc[cb] = a;
    }

    // ---- epilogue: bias add, store, column stats ----
    float s_c[8], q_c[8];
    #pragma unroll
    for (int cb = 0; cb < 8; cb++) {
        int col = cb * 16 + lrow;
        float bc = bias[col];
        float s = 0.f, q = 0.f;
        #pragma unroll
        for (int r = 0; r < 4; r++) {
            int row = row0 + w * 16 + lkg * 4 + r;
            if (row < N_NODES) {
                float v = acc[cb][r] + bc;
                out[(size_t)row * DIM + col] = v;
                s += v; q += v * v;
            }
        }
        s_c[cb] = s; q_c[cb] = q;
    }
    #pragma unroll
    for (int cb = 0; cb < 8; cb++) {
        s_c[cb] += __shfl_xor(s_c[cb], 16); s_c[cb] += __shfl_xor(s_c[cb], 32);
        q_c[cb] += __shfl_xor(q_c[cb], 16); q_c[cb] += __shfl_xor(q_c[cb], 32);
    }
    __syncthreads();                 // done with A_sm, reuse as reduce scratch
    float* red = reinterpret_cast<float*>(A_sm);   // [4 waves][2][128]
    if (lkg == 0) {
        #pragma unroll
        for (int cb = 0; cb < 8; cb++) {
            red[w * 256 + cb * 16 + lrow]       = s_c[cb];
            red[w * 256 + 128 + cb * 16 + lrow] = q_c[cb];
        }
    }
    __syncthreads();
    float* strep = st_out + (blockIdx.x & (NREP - 1)) * 256;
    if (t < 256) {
        // t<128: sum part; t in [128,256): sq part (offset matches layout)
        float v = red[t] + red[256 + t] + red[512 + t] + red[768 + t];
        unsafeAtomicAdd(&strep[t], v);
    }
}

// ---------------- stats of xa = relu(BN(x; stA)) — no data write ----------------
__global__ __launch_bounds__(256) void bn_stats_kernel(
    const float* __restrict__ x, const float* __restrict__ st_in,
    const float* __restrict__ bn_g, const float* __restrict__ bn_b,
    float* __restrict__ st_out)
{
    const int t = threadIdx.x;
    const int cg = t & 31;
    float4 sc, sh;
    bn_coef4(st_in, bn_g, bn_b, cg, sc, sh);
    const float4* x4 = reinterpret_cast<const float4*>(x);
    float4 psum = make_float4(0.f, 0.f, 0.f, 0.f);
    float4 psq  = make_float4(0.f, 0.f, 0.f, 0.f);
    const int total = N_NODES * D4;
    const int stride = gridDim.x * 256;
    for (int idx = blockIdx.x * 256 + t; idx < total; idx += stride) {
        float4 v = x4[idx];
        v.x = fmaxf(fmaf(v.x, sc.x, sh.x), 0.f);
        v.y = fmaxf(fmaf(v.y, sc.y, sh.y), 0.f);
        v.z = fmaxf(fmaf(v.z, sc.z, sh.z), 0.f);
        v.w = fmaxf(fmaf(v.w, sc.w, sh.w), 0.f);
        psum.x += v.x; psum.y += v.y; psum.z += v.z; psum.w += v.w;
        psq.x += v.x * v.x; psq.y += v.y * v.y; psq.z += v.z * v.z; psq.w += v.w * v.w;
    }
    __shared__ float4 red[512];
    red[t]       = psum;
    red[256 + t] = psq;
    __syncthreads();
    if (t < 32) {
        float4 s = make_float4(0.f, 0.f, 0.f, 0.f);
        float4 q = make_float4(0.f, 0.f, 0.f, 0.f);
        #pragma unroll
        for (int r = 0; r < 8; r++) {
            float4 a = red[r * 32 + t];
            float4 b = red[256 + r * 32 + t];
            s.x += a.x; s.y += a.y; s.z += a.z; s.w += a.w;
            q.x += b.x; q.y += b.y; q.z += b.z; q.w += b.w;
        }
        float* strep = st_out + (blockIdx.x & (NREP - 1)) * 256;
        float* gs = strep + t * 4;
        float* gq = strep + 128 + t * 4;
        unsafeAtomicAdd(gs + 0, s.x); unsafeAtomicAdd(gs + 1, s.y);
        unsafeAtomicAdd(gs + 2, s.z); unsafeAtomicAdd(gs + 3, s.w);
        unsafeAtomicAdd(gq + 0, q.x); unsafeAtomicAdd(gq + 1, q.y);
        unsafeAtomicAdd(gq + 2, q.z); unsafeAtomicAdd(gq + 3, q.w);
    }
}

// ---------------- h = relu(BN_o(relu(BN_a(x)))) ----------------
__global__ __launch_bounds__(256) void bn_final_kernel(
    const float* __restrict__ x,
    const float* __restrict__ stA, const float* __restrict__ ga, const float* __restrict__ ba,
    const float* __restrict__ stO, const float* __restrict__ go, const float* __restrict__ bo,
    float* __restrict__ y)
{
    const int t = threadIdx.x;
    const int cg = t & 31;
    float4 sca, sha, sco, sho;
    bn_coef4(stA, ga, ba, cg, sca, sha);
    bn_coef4(stO, go, bo, cg, sco, sho);
    const float4* x4 = reinterpret_cast<const float4*>(x);
    float4* y4 = reinterpret_cast<float4*>(y);
    const int total = N_NODES * D4;
    const int stride = gridDim.x * 256;
    for (int idx = blockIdx.x * 256 + t; idx < total; idx += stride) {
        float4 v = x4[idx];
        v.x = fmaxf(fmaf(v.x, sca.x, sha.x), 0.f);
        v.y = fmaxf(fmaf(v.y, sca.y, sha.y), 0.f);
        v.z = fmaxf(fmaf(v.z, sca.z, sha.z), 0.f);
        v.w = fmaxf(fmaf(v.w, sca.w, sha.w), 0.f);
        v.x = fmaxf(fmaf(v.x, sco.x, sho.x), 0.f);
        v.y = fmaxf(fmaf(v.y, sco.y, sho.y), 0.f);
        v.z = fmaxf(fmaf(v.z, sco.z, sho.z), 0.f);
        v.w = fmaxf(fmaf(v.w, sco.w, sho.w), 0.f);
        y4[idx] = v;
    }
}

extern "C" void kernel_launch(void* const* d_in, const int* in_sizes, int n_in,
                              void* d_out, int out_size, void* d_ws, size_t ws_size,
                              hipStream_t stream)
{
    const float* h0    = (const float*)d_in[0];
    const int*   src   = (const int*)d_in[1];
    const int*   dst   = (const int*)d_in[2];
    const float* ew    = (const float*)d_in[3];
    const float* W1    = (const float*)d_in[4];
    const float* b1    = (const float*)d_in[5];
    const float* bn1_g = (const float*)d_in[6];
    const float* bn1_b = (const float*)d_in[7];
    const float* W2    = (const float*)d_in[8];
    const float* b2    = (const float*)d_in[9];
    const float* bna_g = (const float*)d_in[10];
    const float* bna_b = (const float*)d_in[11];
    const float* bno_g = (const float*)d_in[12];
    const float* bno_b = (const float*)d_in[13];

    float* agg    = (float*)d_ws;                         // N*D (also reused as x2)
    float* xbuf   = agg + (size_t)N_NODES * DIM;          // N*D (x1)
    float* stats  = xbuf + (size_t)N_NODES * DIM;         // 9 * STSZ floats
    int*   counts = (int*)(stats + 9 * STSZ);             // N ints
    int*   offs   = counts + N_NODES;                     // N+1 ints
    int*   cursor = offs + N_NODES + 1;                   // N ints
    int*   bsum   = cursor + N_NODES;                     // 196
    int*   bscan  = bsum + NBLK_SCAN;                     // 196
    int2*  eperm  = (int2*)(((uintptr_t)(bscan + NBLK_SCAN) + 15) & ~(uintptr_t)15); // E int2
    unsigned short* wtg = (unsigned short*)(eperm + N_EDGES);  // 6*128*128 bf16
    float* hout   = (float*)d_out;

    hipMemsetAsync(stats, 0, 9 * STSZ * sizeof(float), stream);
    wt_kernel<<<(6 * DIM * DIM + 255) / 256, 256, 0, stream>>>(W1, W2, wtg);

    const int gemm_grid = (N_NODES + 63) / 64;            // 782
    const int edge_grid = (N_EDGES + 255) / 256;          // 3125
    const int agg_grid  = (N_NODES * 32 + 255) / 256;     // 6250

    for (int i = 0; i < N_LAYERS; i++) {
        const float* hin = (i == 0) ? h0 : hout;
        const int* srcL = src + (size_t)i * N_EDGES;
        const int* dstL = dst + (size_t)i * N_EDGES;
        const float* ewL = ew + (size_t)i * N_EDGES;
        float* st1 = stats + (size_t)(i * 3 + 0) * STSZ;  // NREP x [sum(128)|sq(128)]
        float* stA = stats + (size_t)(i * 3 + 1) * STSZ;
        float* stO = stats + (size_t)(i * 3 + 2) * STSZ;
        const unsigned short* wt1 = wtg + (size_t)i * DIM * DIM;
        const unsigned short* wt2 = wtg + (size_t)(i + 3) * DIM * DIM;

        // --- CSR build + gather aggregation (no float atomics) ---
        hipMemsetAsync(counts, 0, N_NODES * sizeof(int), stream);
        hist_kernel<<<edge_grid, 256, 0, stream>>>(dstL, counts);
        partial_kernel<<<NBLK_SCAN, 256, 0, stream>>>(counts, bsum);
        scan_small_kernel<<<1, 256, 0, stream>>>(bsum, bscan, offs);
        write_offs_kernel<<<NBLK_SCAN, 256, 0, stream>>>(counts, bscan, offs, cursor);
        fill_kernel<<<edge_grid, 256, 0, stream>>>(srcL, dstL, ewL, cursor, eperm);
        agg_kernel<<<agg_grid, 256, 0, stream>>>(hin, offs, eperm, agg);

        gemm_kernel<0><<<gemm_grid, 256, 0, stream>>>(
            hin, agg, nullptr, nullptr, nullptr,
            wt1, b1 + (size_t)i * DIM, xbuf, st1);

        gemm_kernel<1><<<gemm_grid, 256, 0, stream>>>(
            xbuf, nullptr, st1, bn1_g + (size_t)i * DIM, bn1_b + (size_t)i * DIM,
            wt2, b2 + (size_t)i * DIM, agg, stA);

        bn_stats_kernel<<<1024, 256, 0, stream>>>(
            agg, stA, bna_g + (size_t)i * DIM, bna_b + (size_t)i * DIM, stO);

        bn_final_kernel<<<1024, 256, 0, stream>>>(
            agg, stA, bna_g + (size_t)i * DIM, bna_b + (size_t)i * DIM,
            stO, bno_g + (size_t)i * DIM, bno_b + (size_t)i * DIM, hout);
    }
}

// Round 8
// 729.480 us; speedup vs baseline: 6.9740x; 1.1092x over previous
//
#include <hip/hip_runtime.h>

#define N_NODES 50000
#define DIM 128
#define D4 32            // DIM/4
#define D8 16            // DIM/8 (uint4 = 8 bf16 chunks per row)
#define N_EDGES 800000
#define N_LAYERS 3
#define BN_EPS 1e-5f
#define NBLK_SCAN ((N_NODES + 255) / 256)   // 196
#define NREP 16                              // stat replicas (atomic-chain breaker)
#define STSZ (256 * NREP)                    // floats per stat set

typedef __attribute__((ext_vector_type(8))) short bf16x8;
typedef __attribute__((ext_vector_type(4))) float f32x4;

// fp32 -> bf16 round-to-nearest-even
__device__ __forceinline__ unsigned short f2bf(float f) {
    unsigned int u = __float_as_uint(f);
    u = (u + 0x7FFFu + ((u >> 16) & 1u)) >> 16;
    return (unsigned short)u;
}
__device__ __forceinline__ unsigned int pack2(float a, float b) {
    return (unsigned int)f2bf(a) | ((unsigned int)f2bf(b) << 16);
}
__device__ __forceinline__ void bf8_fma(uint4 u, float w, float* acc) {
    acc[0] = fmaf(w, __uint_as_float(u.x << 16), acc[0]);
    acc[1] = fmaf(w, __uint_as_float(u.x & 0xFFFF0000u), acc[1]);
    acc[2] = fmaf(w, __uint_as_float(u.y << 16), acc[2]);
    acc[3] = fmaf(w, __uint_as_float(u.y & 0xFFFF0000u), acc[3]);
    acc[4] = fmaf(w, __uint_as_float(u.z << 16), acc[4]);
    acc[5] = fmaf(w, __uint_as_float(u.z & 0xFFFF0000u), acc[5]);
    acc[6] = fmaf(w, __uint_as_float(u.w << 16), acc[6]);
    acc[7] = fmaf(w, __uint_as_float(u.w & 0xFFFF0000u), acc[7]);
}

// scale/shift from raw BN stats
__device__ __forceinline__ void bn_coef(float sum, float sq, float g, float b,
                                        float& sc, float& sh) {
    float mean = sum * (1.f / N_NODES);
    float var  = sq * (1.f / N_NODES) - mean * mean;
    float rstd = rsqrtf(var + BN_EPS);
    sc = g * rstd;
    sh = b - mean * sc;
}

// sum NREP replicas, then coefs (vector form; cg = float4 column group)
__device__ __forceinline__ void bn_coef4(const float* st,
                                         const float* g, const float* b, int cg,
                                         float4& sc, float4& sh) {
    float4 s = make_float4(0.f, 0.f, 0.f, 0.f);
    float4 q = make_float4(0.f, 0.f, 0.f, 0.f);
    #pragma unroll
    for (int r = 0; r < NREP; r++) {
        const float4* p = reinterpret_cast<const float4*>(st + r * 256);
        float4 a = p[cg];          // sum part
        float4 c = p[32 + cg];     // sq part
        s.x += a.x; s.y += a.y; s.z += a.z; s.w += a.w;
        q.x += c.x; q.y += c.y; q.z += c.z; q.w += c.w;
    }
    float4 gg = reinterpret_cast<const float4*>(g)[cg];
    float4 bb = reinterpret_cast<const float4*>(b)[cg];
    bn_coef(s.x, q.x, gg.x, bb.x, sc.x, sh.x);
    bn_coef(s.y, q.y, gg.y, bb.y, sc.y, sh.y);
    bn_coef(s.z, q.z, gg.z, bb.z, sc.z, sh.z);
    bn_coef(s.w, q.w, gg.w, bb.w, sc.w, sh.w);
}

// ---------------- W transpose + bf16 convert (once per launch, all 6 weights) ----
__global__ __launch_bounds__(256) void wt_kernel(
    const float* __restrict__ W1, const float* __restrict__ W2,
    unsigned short* __restrict__ wtg)
{
    int tid = blockIdx.x * 256 + threadIdx.x;          // 6*16384 total
    if (tid >= 6 * DIM * DIM) return;
    int m = tid >> 14;           // /16384
    int r = tid & 16383;
    int c = r >> 7;              // output row (col of W)
    int k = r & 127;             // output col (row of W)
    const float* src = (m < 3) ? (W1 + (size_t)m * DIM * DIM)
                               : (W2 + (size_t)(m - 3) * DIM * DIM);
    wtg[tid] = f2bf(src[k * DIM + c]);
}

// ---------------- h0 fp32 -> bf16 (layer 0 only) ----------------
__global__ __launch_bounds__(256) void conv0_kernel(
    const float* __restrict__ h, unsigned short* __restrict__ hbf)
{
    int idx = blockIdx.x * 256 + threadIdx.x;          // per 8 elems
    if (idx >= N_NODES * D8) return;
    const float4* h4 = reinterpret_cast<const float4*>(h);
    float4 a = h4[idx * 2], b = h4[idx * 2 + 1];
    uint4 p;
    p.x = pack2(a.x, a.y); p.y = pack2(a.z, a.w);
    p.z = pack2(b.x, b.y); p.w = pack2(b.z, b.w);
    reinterpret_cast<uint4*>(hbf)[idx] = p;
}

// ---------------- CSR build: histogram of dst ----------------
__global__ __launch_bounds__(256) void hist_kernel(
    const int* __restrict__ dst, int* __restrict__ counts)
{
    int e = blockIdx.x * 256 + threadIdx.x;
    if (e < N_EDGES) atomicAdd(&counts[dst[e]], 1);
}

// ---------------- scan stage 1: per-256-chunk sums ----------------
__global__ __launch_bounds__(256) void partial_kernel(
    const int* __restrict__ counts, int* __restrict__ bsum)
{
    __shared__ int s[256];
    int idx = blockIdx.x * 256 + threadIdx.x;
    int v = (idx < N_NODES) ? counts[idx] : 0;
    s[threadIdx.x] = v;
    __syncthreads();
    #pragma unroll
    for (int off = 128; off > 0; off >>= 1) {
        if (threadIdx.x < off) s[threadIdx.x] += s[threadIdx.x + off];
        __syncthreads();
    }
    if (threadIdx.x == 0) bsum[blockIdx.x] = s[0];
}

// ---------------- scan stage 2: scan the 196 block sums ----------------
__global__ __launch_bounds__(256) void scan_small_kernel(
    const int* __restrict__ bsum, int* __restrict__ bscan, int* __restrict__ offsets)
{
    __shared__ int s[256];
    int t = threadIdx.x;
    int v = (t < NBLK_SCAN) ? bsum[t] : 0;
    s[t] = v;
    __syncthreads();
    #pragma unroll
    for (int off = 1; off < 256; off <<= 1) {
        int u = (t >= off) ? s[t - off] : 0;
        __syncthreads();
        s[t] += u;
        __syncthreads();
    }
    if (t < NBLK_SCAN) bscan[t] = s[t] - v;     // exclusive
    if (t == 255) offsets[N_NODES] = s[255];    // total (= N_EDGES)
}

// ---------------- scan stage 3: per-chunk exclusive scan + base ----------------
__global__ __launch_bounds__(256) void write_offs_kernel(
    const int* __restrict__ counts, const int* __restrict__ bscan,
    int* __restrict__ offsets, int* __restrict__ cursor)
{
    __shared__ int s[256];
    int t = threadIdx.x;
    int idx = blockIdx.x * 256 + t;
    int v = (idx < N_NODES) ? counts[idx] : 0;
    s[t] = v;
    __syncthreads();
    #pragma unroll
    for (int off = 1; off < 256; off <<= 1) {
        int u = (t >= off) ? s[t - off] : 0;
        __syncthreads();
        s[t] += u;
        __syncthreads();
    }
    int ex = s[t] - v + bscan[blockIdx.x];
    if (idx < N_NODES) { offsets[idx] = ex; cursor[idx] = ex; }
}

// ---------------- CSR build: fill permuted (src, weight) ----------------
__global__ __launch_bounds__(256) void fill_kernel(
    const int* __restrict__ src, const int* __restrict__ dst,
    const float* __restrict__ ew, int* __restrict__ cursor,
    int2* __restrict__ eperm)
{
    int e = blockIdx.x * 256 + threadIdx.x;
    if (e >= N_EDGES) return;
    int pos = atomicAdd(&cursor[dst[e]], 1);
    eperm[pos] = make_int2(src[e], __float_as_int(ew[e]));
}

// ---- aggregate + self: rbf[n] = bf16( h[n] + sum_{e: dst=n} w_e * h[src_e] ) ----
// 16 lanes per node, bf16 gather (uint4 = 8 bf16 per lane), fp32 accumulate.
__global__ __launch_bounds__(256) void agg_kernel(
    const unsigned short* __restrict__ hbf, const int* __restrict__ offsets,
    const int2* __restrict__ eperm, unsigned short* __restrict__ rbf)
{
    int gid = blockIdx.x * 256 + threadIdx.x;
    int node = gid >> 4;
    if (node >= N_NODES) return;
    int lane = gid & 15;
    const uint4* h4 = reinterpret_cast<const uint4*>(hbf);
    int cidx = node * D8 + lane;
    float acc[8] = {0.f, 0.f, 0.f, 0.f, 0.f, 0.f, 0.f, 0.f};
    bf8_fma(h4[cidx], 1.0f, acc);                 // self term (eps = 0)
    int beg = offsets[node], end = offsets[node + 1];
    for (int j = beg; j < end; j++) {
        int2 e = eperm[j];
        float w = __int_as_float(e.y);
        bf8_fma(h4[e.x * D8 + lane], w, acc);
    }
    uint4 p;
    p.x = pack2(acc[0], acc[1]); p.y = pack2(acc[2], acc[3]);
    p.z = pack2(acc[4], acc[5]); p.w = pack2(acc[6], acc[7]);
    reinterpret_cast<uint4*>(rbf)[cidx] = p;
}

// ---------------- MFMA GEMM: out = f(in) @ W + bias, + column stats ----------------
// MODE 0: in = rbf (pre-staged bf16)     (GEMM1)
// MODE 1: in = relu(BN(A; st,g,b))       (GEMM2: BN1+ReLU fused on staging)
template<int MODE>
__global__ __launch_bounds__(256) void gemm_kernel(
    const unsigned short* __restrict__ Abf, const float* __restrict__ A,
    const float* __restrict__ st_in, const float* __restrict__ bn_g,
    const float* __restrict__ bn_b,
    const unsigned short* __restrict__ Wt, const float* __restrict__ bias,
    float* __restrict__ out, float* __restrict__ st_out)
{
    __shared__ unsigned short A_sm[64 * DIM];    // 16 KB bf16, XOR-swizzled
    __shared__ unsigned short W_sm[DIM * DIM];   // 32 KB bf16 W^T, XOR-swizzled
    __shared__ float2 scsh[DIM];                 // BN coefs (MODE 1)

    const int t = threadIdx.x;
    const int row0 = blockIdx.x * 64;

    if (MODE == 1) {
        if (t < 128) {
            float ssum = 0.f, ssq = 0.f;
            #pragma unroll
            for (int r = 0; r < NREP; r++) {
                ssum += st_in[r * 256 + t];
                ssq  += st_in[r * 256 + 128 + t];
            }
            float sc, sh;
            bn_coef(ssum, ssq, bn_g[t], bn_b[t], sc, sh);
            scsh[t] = make_float2(sc, sh);
        }
        __syncthreads();
    }

    // ---- stage W^T (already bf16, c-major): 2048 16B chunks ----
    {
        const uint4* wsrc = reinterpret_cast<const uint4*>(Wt);
        #pragma unroll
        for (int j = 0; j < 8; j++) {
            int id = t + j * 256;            // 0..2047
            int c  = id >> 4;
            int kc = id & 15;
            int sidx = (c * DIM + kc * 8) ^ ((c & 7) << 3);
            *reinterpret_cast<uint4*>(&W_sm[sidx]) = wsrc[id];
        }
    }

    // ---- stage A tile (swizzled) ----
    if (MODE == 0) {
        const uint4* asrc = reinterpret_cast<const uint4*>(Abf);
        #pragma unroll
        for (int j = 0; j < 4; j++) {
            int id = t + j * 256;            // 0..1023
            int r  = id >> 4;                // tile row 0..63
            int kc = id & 15;
            int row = row0 + r;
            uint4 u = make_uint4(0u, 0u, 0u, 0u);
            if (row < N_NODES) u = asrc[row * D8 + kc];
            int sidx = (r * DIM + kc * 8) ^ ((r & 7) << 3);
            *reinterpret_cast<uint4*>(&A_sm[sidx]) = u;
        }
    } else {
        const float4* A4 = reinterpret_cast<const float4*>(A);
        #pragma unroll
        for (int j = 0; j < 8; j++) {
            int id = t + j * 256;            // 0..2047
            int r  = id >> 5;                // tile row 0..63
            int q  = id & 31;                // float4 col group
            int row = row0 + r;
            float4 v = make_float4(0.f, 0.f, 0.f, 0.f);
            if (row < N_NODES) {
                float4 a = A4[(size_t)row * D4 + q];
                float2 c0 = scsh[q * 4 + 0], c1 = scsh[q * 4 + 1];
                float2 c2 = scsh[q * 4 + 2], c3 = scsh[q * 4 + 3];
                v.x = fmaxf(fmaf(a.x, c0.x, c0.y), 0.f);
                v.y = fmaxf(fmaf(a.y, c1.x, c1.y), 0.f);
                v.z = fmaxf(fmaf(a.z, c2.x, c2.y), 0.f);
                v.w = fmaxf(fmaf(a.w, c3.x, c3.y), 0.f);
            }
            ushort4 u = make_ushort4(f2bf(v.x), f2bf(v.y), f2bf(v.z), f2bf(v.w));
            int sidx = (r * DIM + q * 4) ^ ((r & 7) << 3);
            *reinterpret_cast<ushort4*>(&A_sm[sidx]) = u;
        }
    }
    __syncthreads();

    // ---- MFMA: wave w owns rows w*16..w*16+15, all 8 col-blocks ----
    const int w    = t >> 6;
    const int lane = t & 63;
    const int lrow = lane & 15;
    const int lkg  = lane >> 4;
    const int arow = w * 16 + lrow;

    bf16x8 afr[4];
    #pragma unroll
    for (int ks = 0; ks < 4; ks++) {
        int k = ks * 32 + lkg * 8;
        int idx = (arow * DIM + k) ^ ((arow & 7) << 3);
        afr[ks] = *reinterpret_cast<const bf16x8*>(&A_sm[idx]);
    }

    f32x4 acc[8];
    #pragma unroll
    for (int cb = 0; cb < 8; cb++) {
        f32x4 a = {0.f, 0.f, 0.f, 0.f};
        int col = cb * 16 + lrow;
        #pragma unroll
        for (int ks = 0; ks < 4; ks++) {
            int k = ks * 32 + lkg * 8;
            int widx = (col * DIM + k) ^ ((col & 7) << 3);
            bf16x8 bfr = *reinterpret_cast<const bf16x8*>(&W_sm[widx]);
            a = __builtin_amdgcn_mfma_f32_16x16x32_bf16(afr[ks], bfr, a, 0, 0, 0);
        }
        acc[cb] = a;
    }

    // ---- epilogue: bias add, store, column stats ----
    float s_c[8], q_c[8];
    #pragma unroll
    for (int cb = 0; cb < 8; cb++) {
        int col = cb * 16 + lrow;
        float bc = bias[col];
        float s = 0.f, q = 0.f;
        #pragma unroll
        for (int r = 0; r < 4; r++) {
            int row = row0 + w * 16 + lkg * 4 + r;
            if (row < N_NODES) {
                float v = acc[cb][r] + bc;
                out[(size_t)row * DIM + col] = v;
                s += v; q += v * v;
            }
        }
        s_c[cb] = s; q_c[cb] = q;
    }
    #pragma unroll
    for (int cb = 0; cb < 8; cb++) {
        s_c[cb] += __shfl_xor(s_c[cb], 16); s_c[cb] += __shfl_xor(s_c[cb], 32);
        q_c[cb] += __shfl_xor(q_c[cb], 16); q_c[cb] += __shfl_xor(q_c[cb], 32);
    }
    __syncthreads();                 // done with A_sm, reuse as reduce scratch
    float* red = reinterpret_cast<float*>(A_sm);   // [4 waves][2][128]
    if (lkg == 0) {
        #pragma unroll
        for (int cb = 0; cb < 8; cb++) {
            red[w * 256 + cb * 16 + lrow]       = s_c[cb];
            red[w * 256 + 128 + cb * 16 + lrow] = q_c[cb];
        }
    }
    __syncthreads();
    float* strep = st_out + (blockIdx.x & (NREP - 1)) * 256;
    if (t < 256) {
        float v = red[t] + red[256 + t] + red[512 + t] + red[768 + t];
        unsafeAtomicAdd(&strep[t], v);
    }
}

// ---------------- stats of xa = relu(BN(x; stA)) — no data write ----------------
__global__ __launch_bounds__(256) void bn_stats_kernel(
    const float* __restrict__ x, const float* __restrict__ st_in,
    const float* __restrict__ bn_g, const float* __restrict__ bn_b,
    float* __restrict__ st_out)
{
    const int t = threadIdx.x;
    const int cg = t & 31;
    float4 sc, sh;
    bn_coef4(st_in, bn_g, bn_b, cg, sc, sh);
    const float4* x4 = reinterpret_cast<const float4*>(x);
    float4 psum = make_float4(0.f, 0.f, 0.f, 0.f);
    float4 psq  = make_float4(0.f, 0.f, 0.f, 0.f);
    const int total = N_NODES * D4;
    const int stride = gridDim.x * 256;
    for (int idx = blockIdx.x * 256 + t; idx < total; idx += stride) {
        float4 v = x4[idx];
        v.x = fmaxf(fmaf(v.x, sc.x, sh.x), 0.f);
        v.y = fmaxf(fmaf(v.y, sc.y, sh.y), 0.f);
        v.z = fmaxf(fmaf(v.z, sc.z, sh.z), 0.f);
        v.w = fmaxf(fmaf(v.w, sc.w, sh.w), 0.f);
        psum.x += v.x; psum.y += v.y; psum.z += v.z; psum.w += v.w;
        psq.x += v.x * v.x; psq.y += v.y * v.y; psq.z += v.z * v.z; psq.w += v.w * v.w;
    }
    __shared__ float4 red[512];
    red[t]       = psum;
    red[256 + t] = psq;
    __syncthreads();
    if (t < 32) {
        float4 s = make_float4(0.f, 0.f, 0.f, 0.f);
        float4 q = make_float4(0.f, 0.f, 0.f, 0.f);
        #pragma unroll
        for (int r = 0; r < 8; r++) {
            float4 a = red[r * 32 + t];
            float4 b = red[256 + r * 32 + t];
            s.x += a.x; s.y += a.y; s.z += a.z; s.w += a.w;
            q.x += b.x; q.y += b.y; q.z += b.z; q.w += b.w;
        }
        float* strep = st_out + (blockIdx.x & (NREP - 1)) * 256;
        float* gs = strep + t * 4;
        float* gq = strep + 128 + t * 4;
        unsafeAtomicAdd(gs + 0, s.x); unsafeAtomicAdd(gs + 1, s.y);
        unsafeAtomicAdd(gs + 2, s.z); unsafeAtomicAdd(gs + 3, s.w);
        unsafeAtomicAdd(gq + 0, q.x); unsafeAtomicAdd(gq + 1, q.y);
        unsafeAtomicAdd(gq + 2, q.z); unsafeAtomicAdd(gq + 3, q.w);
    }
}

// ---------------- h = relu(BN_o(relu(BN_a(x)))) ----------------
// LAST=0: write bf16 h only (next layer input). LAST=1: write fp32 d_out only.
template<int LAST>
__global__ __launch_bounds__(256) void bn_final_kernel(
    const float* __restrict__ x,
    const float* __restrict__ stA, const float* __restrict__ ga, const float* __restrict__ ba,
    const float* __restrict__ stO, const float* __restrict__ go, const float* __restrict__ bo,
    float* __restrict__ y, unsigned short* __restrict__ ybf)
{
    const int t = threadIdx.x;
    const int cg = t & 31;
    float4 sca, sha, sco, sho;
    bn_coef4(stA, ga, ba, cg, sca, sha);
    bn_coef4(stO, go, bo, cg, sco, sho);
    const float4* x4 = reinterpret_cast<const float4*>(x);
    float4* y4 = reinterpret_cast<float4*>(y);
    const int total = N_NODES * D4;
    const int stride = gridDim.x * 256;
    for (int idx = blockIdx.x * 256 + t; idx < total; idx += stride) {
        float4 v = x4[idx];
        v.x = fmaxf(fmaf(v.x, sca.x, sha.x), 0.f);
        v.y = fmaxf(fmaf(v.y, sca.y, sha.y), 0.f);
        v.z = fmaxf(fmaf(v.z, sca.z, sha.z), 0.f);
        v.w = fmaxf(fmaf(v.w, sca.w, sha.w), 0.f);
        v.x = fmaxf(fmaf(v.x, sco.x, sho.x), 0.f);
        v.y = fmaxf(fmaf(v.y, sco.y, sho.y), 0.f);
        v.z = fmaxf(fmaf(v.z, sco.z, sho.z), 0.f);
        v.w = fmaxf(fmaf(v.w, sco.w, sho.w), 0.f);
        if (LAST) {
            y4[idx] = v;
        } else {
            ushort4 u = make_ushort4(f2bf(v.x), f2bf(v.y), f2bf(v.z), f2bf(v.w));
            reinterpret_cast<ushort4*>(ybf)[idx] = u;
        }
    }
}

extern "C" void kernel_launch(void* const* d_in, const int* in_sizes, int n_in,
                              void* d_out, int out_size, void* d_ws, size_t ws_size,
                              hipStream_t stream)
{
    const float* h0    = (const float*)d_in[0];
    const int*   src   = (const int*)d_in[1];
    const int*   dst   = (const int*)d_in[2];
    const float* ew    = (const float*)d_in[3];
    const float* W1    = (const float*)d_in[4];
    const float* b1    = (const float*)d_in[5];
    const float* bn1_g = (const float*)d_in[6];
    const float* bn1_b = (const float*)d_in[7];
    const float* W2    = (const float*)d_in[8];
    const float* b2    = (const float*)d_in[9];
    const float* bna_g = (const float*)d_in[10];
    const float* bna_b = (const float*)d_in[11];
    const float* bno_g = (const float*)d_in[12];
    const float* bno_b = (const float*)d_in[13];

    const size_t ND = (size_t)N_NODES * DIM;
    float* R0     = (float*)d_ws;                         // N*D floats
    float* R1     = R0 + ND;                              // N*D floats
    float* stats  = R1 + ND;                              // 9 * STSZ floats
    int*   counts = (int*)(stats + 9 * STSZ);             // N ints
    int*   offs   = counts + N_NODES;                     // N+1 ints
    int*   cursor = offs + N_NODES + 1;                   // N ints
    int*   bsum   = cursor + N_NODES;                     // 196
    int*   bscan  = bsum + NBLK_SCAN;                     // 196
    int2*  eperm  = (int2*)(((uintptr_t)(bscan + NBLK_SCAN) + 15) & ~(uintptr_t)15); // E int2
    unsigned short* wtg = (unsigned short*)(eperm + N_EDGES);  // 6*128*128 bf16
    float* hout   = (float*)d_out;

    hipMemsetAsync(stats, 0, 9 * STSZ * sizeof(float), stream);
    wt_kernel<<<(6 * DIM * DIM + 255) / 256, 256, 0, stream>>>(W1, W2, wtg);
    conv0_kernel<<<(N_NODES * D8 + 255) / 256, 256, 0, stream>>>(h0, (unsigned short*)R0);

    const int gemm_grid = (N_NODES + 63) / 64;            // 782
    const int edge_grid = (N_EDGES + 255) / 256;          // 3125
    const int agg_grid  = (N_NODES * 16 + 255) / 256;     // 3125

    for (int i = 0; i < N_LAYERS; i++) {
        const int* srcL = src + (size_t)i * N_EDGES;
        const int* dstL = dst + (size_t)i * N_EDGES;
        const float* ewL = ew + (size_t)i * N_EDGES;
        float* st1 = stats + (size_t)(i * 3 + 0) * STSZ;  // NREP x [sum(128)|sq(128)]
        float* stA = stats + (size_t)(i * 3 + 1) * STSZ;
        float* stO = stats + (size_t)(i * 3 + 2) * STSZ;
        const unsigned short* wt1 = wtg + (size_t)i * DIM * DIM;
        const unsigned short* wt2 = wtg + (size_t)(i + 3) * DIM * DIM;

        // ping-pong regions: even layers h/r in R0, odd layers in R1
        float* Re = (i & 1) ? R1 : R0;
        float* Ro = (i & 1) ? R0 : R1;
        unsigned short* hbf = (unsigned short*)Re;        // first half of Re
        unsigned short* rbf = (unsigned short*)Re + ND;   // second half of Re
        float* x1 = Ro;
        float* x2 = Re;                                   // clobbers hbf+rbf (dead)
        unsigned short* ybf = (unsigned short*)Ro;        // next layer's hbf

        // --- CSR build + bf16 gather aggregation ---
        hipMemsetAsync(counts, 0, N_NODES * sizeof(int), stream);
        hist_kernel<<<edge_grid, 256, 0, stream>>>(dstL, counts);
        partial_kernel<<<NBLK_SCAN, 256, 0, stream>>>(counts, bsum);
        scan_small_kernel<<<1, 256, 0, stream>>>(bsum, bscan, offs);
        write_offs_kernel<<<NBLK_SCAN, 256, 0, stream>>>(counts, bscan, offs, cursor);
        fill_kernel<<<edge_grid, 256, 0, stream>>>(srcL, dstL, ewL, cursor, eperm);
        agg_kernel<<<agg_grid, 256, 0, stream>>>(hbf, offs, eperm, rbf);

        gemm_kernel<0><<<gemm_grid, 256, 0, stream>>>(
            rbf, nullptr, nullptr, nullptr, nullptr,
            wt1, b1 + (size_t)i * DIM, x1, st1);

        gemm_kernel<1><<<gemm_grid, 256, 0, stream>>>(
            nullptr, x1, st1, bn1_g + (size_t)i * DIM, bn1_b + (size_t)i * DIM,
            wt2, b2 + (size_t)i * DIM, x2, stA);

        bn_stats_kernel<<<1024, 256, 0, stream>>>(
            x2, stA, bna_g + (size_t)i * DIM, bna_b + (size_t)i * DIM, stO);

        if (i == N_LAYERS - 1) {
            bn_final_kernel<1><<<1024, 256, 0, stream>>>(
                x2, stA, bna_g + (size_t)i * DIM, bna_b + (size_t)i * DIM,
                stO, bno_g + (size_t)i * DIM, bno_b + (size_t)i * DIM, hout, nullptr);
        } else {
            bn_final_kernel<0><<<1024, 256, 0, stream>>>(
                x2, stA, bna_g + (size_t)i * DIM, bna_b + (size_t)i * DIM,
                stO, bno_g + (size_t)i * DIM, bno_b + (size_t)i * DIM, nullptr, ybf);
        }
    }
}

// Round 9
// 720.829 us; speedup vs baseline: 7.0577x; 1.0120x over previous
//
#include <hip/hip_runtime.h>

#define N_NODES 50000
#define DIM 128
#define D4 32            // DIM/4
#define D8 16            // DIM/8 (uint4 = 8 bf16 chunks per row)
#define N_EDGES 800000
#define N_LAYERS 3
#define BN_EPS 1e-5f
#define NBLK_SCAN ((N_NODES + 255) / 256)   // 196
#define NREP 16                              // stat replicas (atomic-chain breaker)
#define STSZ (256 * NREP)                    // floats per stat set
#define NWIN 8                               // fill windows (dst-space partitions)
#define WIN_NODES (N_NODES / NWIN)           // 6250
#define EDGE_BLKS ((N_EDGES + 255) / 256)    // 3125

typedef __attribute__((ext_vector_type(8))) short bf16x8;
typedef __attribute__((ext_vector_type(4))) float f32x4;

// fp32 -> bf16 round-to-nearest-even
__device__ __forceinline__ unsigned short f2bf(float f) {
    unsigned int u = __float_as_uint(f);
    u = (u + 0x7FFFu + ((u >> 16) & 1u)) >> 16;
    return (unsigned short)u;
}
__device__ __forceinline__ unsigned int pack2(float a, float b) {
    return (unsigned int)f2bf(a) | ((unsigned int)f2bf(b) << 16);
}
__device__ __forceinline__ void bf8_fma(uint4 u, float w, float* acc) {
    acc[0] = fmaf(w, __uint_as_float(u.x << 16), acc[0]);
    acc[1] = fmaf(w, __uint_as_float(u.x & 0xFFFF0000u), acc[1]);
    acc[2] = fmaf(w, __uint_as_float(u.y << 16), acc[2]);
    acc[3] = fmaf(w, __uint_as_float(u.y & 0xFFFF0000u), acc[3]);
    acc[4] = fmaf(w, __uint_as_float(u.z << 16), acc[4]);
    acc[5] = fmaf(w, __uint_as_float(u.z & 0xFFFF0000u), acc[5]);
    acc[6] = fmaf(w, __uint_as_float(u.w << 16), acc[6]);
    acc[7] = fmaf(w, __uint_as_float(u.w & 0xFFFF0000u), acc[7]);
}

// scale/shift from raw BN stats
__device__ __forceinline__ void bn_coef(float sum, float sq, float g, float b,
                                        float& sc, float& sh) {
    float mean = sum * (1.f / N_NODES);
    float var  = sq * (1.f / N_NODES) - mean * mean;
    float rstd = rsqrtf(var + BN_EPS);
    sc = g * rstd;
    sh = b - mean * sc;
}

// sum NREP replicas, then coefs (vector form; cg = float4 column group)
__device__ __forceinline__ void bn_coef4(const float* st,
                                         const float* g, const float* b, int cg,
                                         float4& sc, float4& sh) {
    float4 s = make_float4(0.f, 0.f, 0.f, 0.f);
    float4 q = make_float4(0.f, 0.f, 0.f, 0.f);
    #pragma unroll
    for (int r = 0; r < NREP; r++) {
        const float4* p = reinterpret_cast<const float4*>(st + r * 256);
        float4 a = p[cg];          // sum part
        float4 c = p[32 + cg];     // sq part
        s.x += a.x; s.y += a.y; s.z += a.z; s.w += a.w;
        q.x += c.x; q.y += c.y; q.z += c.z; q.w += c.w;
    }
    float4 gg = reinterpret_cast<const float4*>(g)[cg];
    float4 bb = reinterpret_cast<const float4*>(b)[cg];
    bn_coef(s.x, q.x, gg.x, bb.x, sc.x, sh.x);
    bn_coef(s.y, q.y, gg.y, bb.y, sc.y, sh.y);
    bn_coef(s.z, q.z, gg.z, bb.z, sc.z, sh.z);
    bn_coef(s.w, q.w, gg.w, bb.w, sc.w, sh.w);
}

// ---------------- W transpose + bf16 convert (once per launch, all 6 weights) ----
__global__ __launch_bounds__(256) void wt_kernel(
    const float* __restrict__ W1, const float* __restrict__ W2,
    unsigned short* __restrict__ wtg)
{
    int tid = blockIdx.x * 256 + threadIdx.x;          // 6*16384 total
    if (tid >= 6 * DIM * DIM) return;
    int m = tid >> 14;           // /16384
    int r = tid & 16383;
    int c = r >> 7;              // output row (col of W)
    int k = r & 127;             // output col (row of W)
    const float* src = (m < 3) ? (W1 + (size_t)m * DIM * DIM)
                               : (W2 + (size_t)(m - 3) * DIM * DIM);
    wtg[tid] = f2bf(src[k * DIM + c]);
}

// ---------------- h0 fp32 -> bf16 (layer 0 only) ----------------
__global__ __launch_bounds__(256) void conv0_kernel(
    const float* __restrict__ h, unsigned short* __restrict__ hbf)
{
    int idx = blockIdx.x * 256 + threadIdx.x;          // per 8 elems
    if (idx >= N_NODES * D8) return;
    const float4* h4 = reinterpret_cast<const float4*>(h);
    float4 a = h4[idx * 2], b = h4[idx * 2 + 1];
    uint4 p;
    p.x = pack2(a.x, a.y); p.y = pack2(a.z, a.w);
    p.z = pack2(b.x, b.y); p.w = pack2(b.z, b.w);
    reinterpret_cast<uint4*>(hbf)[idx] = p;
}

// ---------------- CSR build: histogram of dst ----------------
__global__ __launch_bounds__(256) void hist_kernel(
    const int* __restrict__ dst, int* __restrict__ counts)
{
    int e = blockIdx.x * 256 + threadIdx.x;
    if (e < N_EDGES) atomicAdd(&counts[dst[e]], 1);
}

// ---------------- scan stage 1: per-256-chunk sums ----------------
__global__ __launch_bounds__(256) void partial_kernel(
    const int* __restrict__ counts, int* __restrict__ bsum)
{
    __shared__ int s[256];
    int idx = blockIdx.x * 256 + threadIdx.x;
    int v = (idx < N_NODES) ? counts[idx] : 0;
    s[threadIdx.x] = v;
    __syncthreads();
    #pragma unroll
    for (int off = 128; off > 0; off >>= 1) {
        if (threadIdx.x < off) s[threadIdx.x] += s[threadIdx.x + off];
        __syncthreads();
    }
    if (threadIdx.x == 0) bsum[blockIdx.x] = s[0];
}

// ---- scan stage 2 (fused): inline scan of bsum + per-chunk scan + base ----
__global__ __launch_bounds__(256) void write_offs_kernel(
    const int* __restrict__ counts, const int* __restrict__ bsum,
    int* __restrict__ offsets, int* __restrict__ cursor)
{
    __shared__ int sb[256];
    __shared__ int s[256];
    int t = threadIdx.x;
    // every block redundantly scans the 196 block sums (cheap, removes a launch)
    int bv = (t < NBLK_SCAN) ? bsum[t] : 0;
    sb[t] = bv;
    __syncthreads();
    #pragma unroll
    for (int off = 1; off < 256; off <<= 1) {
        int u = (t >= off) ? sb[t - off] : 0;
        __syncthreads();
        sb[t] += u;
        __syncthreads();
    }
    int base = (blockIdx.x == 0) ? 0 : sb[blockIdx.x - 1];   // exclusive block prefix
    if (blockIdx.x == 0 && t == 0) offsets[N_NODES] = sb[255];

    int idx = blockIdx.x * 256 + t;
    int v = (idx < N_NODES) ? counts[idx] : 0;
    s[t] = v;
    __syncthreads();
    #pragma unroll
    for (int off = 1; off < 256; off <<= 1) {
        int u = (t >= off) ? s[t - off] : 0;
        __syncthreads();
        s[t] += u;
        __syncthreads();
    }
    int ex = s[t] - v + base;
    if (idx < N_NODES) { offsets[idx] = ex; cursor[idx] = ex; }
}

// ---------------- CSR fill, dst-windowed for L2 write locality ----------------
// grid = NWIN * EDGE_BLKS; window w's blocks only emit edges with dst in window w,
// so each ~800KB eperm region is written while L2-resident (fixes 64B write-allocate
// blowup: 52MB -> ~6.4MB effective writes).
__global__ __launch_bounds__(256) void fill_kernel(
    const int* __restrict__ src, const int* __restrict__ dst,
    const float* __restrict__ ew, int* __restrict__ cursor,
    int2* __restrict__ eperm)
{
    int w = blockIdx.x / EDGE_BLKS;
    int e = (blockIdx.x - w * EDGE_BLKS) * 256 + threadIdx.x;
    if (e >= N_EDGES) return;
    int d = dst[e];
    int lo = w * WIN_NODES;
    if (d < lo || d >= lo + WIN_NODES) return;
    int pos = atomicAdd(&cursor[d], 1);
    eperm[pos] = make_int2(src[e], __float_as_int(ew[e]));
}

// ---- aggregate + self: rbf[n] = bf16( h[n] + sum_{e: dst=n} w_e * h[src_e] ) ----
// 16 lanes per node, bf16 gather (uint4 = 8 bf16 per lane), fp32 accumulate.
__global__ __launch_bounds__(256) void agg_kernel(
    const unsigned short* __restrict__ hbf, const int* __restrict__ offsets,
    const int2* __restrict__ eperm, unsigned short* __restrict__ rbf)
{
    int gid = blockIdx.x * 256 + threadIdx.x;
    int node = gid >> 4;
    if (node >= N_NODES) return;
    int lane = gid & 15;
    const uint4* h4 = reinterpret_cast<const uint4*>(hbf);
    int cidx = node * D8 + lane;
    float acc[8] = {0.f, 0.f, 0.f, 0.f, 0.f, 0.f, 0.f, 0.f};
    bf8_fma(h4[cidx], 1.0f, acc);                 // self term (eps = 0)
    int beg = offsets[node], end = offsets[node + 1];
    for (int j = beg; j < end; j++) {
        int2 e = eperm[j];
        float w = __int_as_float(e.y);
        bf8_fma(h4[e.x * D8 + lane], w, acc);
    }
    uint4 p;
    p.x = pack2(acc[0], acc[1]); p.y = pack2(acc[2], acc[3]);
    p.z = pack2(acc[4], acc[5]); p.w = pack2(acc[6], acc[7]);
    reinterpret_cast<uint4*>(rbf)[cidx] = p;
}

// ---------------- MFMA GEMM: out = f(in) @ W + bias, + column stats ----------------
// MODE 0: in = rbf (pre-staged bf16)     (GEMM1)
// MODE 1: in = relu(BN(A; st,g,b))       (GEMM2: BN1+ReLU fused on staging)
template<int MODE>
__global__ __launch_bounds__(256) void gemm_kernel(
    const unsigned short* __restrict__ Abf, const float* __restrict__ A,
    const float* __restrict__ st_in, const float* __restrict__ bn_g,
    const float* __restrict__ bn_b,
    const unsigned short* __restrict__ Wt, const float* __restrict__ bias,
    float* __restrict__ out, float* __restrict__ st_out)
{
    __shared__ unsigned short A_sm[64 * DIM];    // 16 KB bf16, XOR-swizzled
    __shared__ unsigned short W_sm[DIM * DIM];   // 32 KB bf16 W^T, XOR-swizzled
    __shared__ float2 scsh[DIM];                 // BN coefs (MODE 1)

    const int t = threadIdx.x;
    const int row0 = blockIdx.x * 64;

    if (MODE == 1) {
        if (t < 128) {
            float ssum = 0.f, ssq = 0.f;
            #pragma unroll
            for (int r = 0; r < NREP; r++) {
                ssum += st_in[r * 256 + t];
                ssq  += st_in[r * 256 + 128 + t];
            }
            float sc, sh;
            bn_coef(ssum, ssq, bn_g[t], bn_b[t], sc, sh);
            scsh[t] = make_float2(sc, sh);
        }
        __syncthreads();
    }

    // ---- stage W^T (already bf16, c-major): 2048 16B chunks ----
    {
        const uint4* wsrc = reinterpret_cast<const uint4*>(Wt);
        #pragma unroll
        for (int j = 0; j < 8; j++) {
            int id = t + j * 256;            // 0..2047
            int c  = id >> 4;
            int kc = id & 15;
            int sidx = (c * DIM + kc * 8) ^ ((c & 7) << 3);
            *reinterpret_cast<uint4*>(&W_sm[sidx]) = wsrc[id];
        }
    }

    // ---- stage A tile (swizzled) ----
    if (MODE == 0) {
        const uint4* asrc = reinterpret_cast<const uint4*>(Abf);
        #pragma unroll
        for (int j = 0; j < 4; j++) {
            int id = t + j * 256;            // 0..1023
            int r  = id >> 4;                // tile row 0..63
            int kc = id & 15;
            int row = row0 + r;
            uint4 u = make_uint4(0u, 0u, 0u, 0u);
            if (row < N_NODES) u = asrc[row * D8 + kc];
            int sidx = (r * DIM + kc * 8) ^ ((r & 7) << 3);
            *reinterpret_cast<uint4*>(&A_sm[sidx]) = u;
        }
    } else {
        const float4* A4 = reinterpret_cast<const float4*>(A);
        #pragma unroll
        for (int j = 0; j < 8; j++) {
            int id = t + j * 256;            // 0..2047
            int r  = id >> 5;                // tile row 0..63
            int q  = id & 31;                // float4 col group
            int row = row0 + r;
            float4 v = make_float4(0.f, 0.f, 0.f, 0.f);
            if (row < N_NODES) {
                float4 a = A4[(size_t)row * D4 + q];
                float2 c0 = scsh[q * 4 + 0], c1 = scsh[q * 4 + 1];
                float2 c2 = scsh[q * 4 + 2], c3 = scsh[q * 4 + 3];
                v.x = fmaxf(fmaf(a.x, c0.x, c0.y), 0.f);
                v.y = fmaxf(fmaf(a.y, c1.x, c1.y), 0.f);
                v.z = fmaxf(fmaf(a.z, c2.x, c2.y), 0.f);
                v.w = fmaxf(fmaf(a.w, c3.x, c3.y), 0.f);
            }
            ushort4 u = make_ushort4(f2bf(v.x), f2bf(v.y), f2bf(v.z), f2bf(v.w));
            int sidx = (r * DIM + q * 4) ^ ((r & 7) << 3);
            *reinterpret_cast<ushort4*>(&A_sm[sidx]) = u;
        }
    }
    __syncthreads();

    // ---- MFMA: wave w owns rows w*16..w*16+15, all 8 col-blocks ----
    const int w    = t >> 6;
    const int lane = t & 63;
    const int lrow = lane & 15;
    const int lkg  = lane >> 4;
    const int arow = w * 16 + lrow;

    bf16x8 afr[4];
    #pragma unroll
    for (int ks = 0; ks < 4; ks++) {
        int k = ks * 32 + lkg * 8;
        int idx = (arow * DIM + k) ^ ((arow & 7) << 3);
        afr[ks] = *reinterpret_cast<const bf16x8*>(&A_sm[idx]);
    }

    f32x4 acc[8];
    #pragma unroll
    for (int cb = 0; cb < 8; cb++) {
        f32x4 a = {0.f, 0.f, 0.f, 0.f};
        int col = cb * 16 + lrow;
        #pragma unroll
        for (int ks = 0; ks < 4; ks++) {
            int k = ks * 32 + lkg * 8;
            int widx = (col * DIM + k) ^ ((col & 7) << 3);
            bf16x8 bfr = *reinterpret_cast<const bf16x8*>(&W_sm[widx]);
            a = __builtin_amdgcn_mfma_f32_16x16x32_bf16(afr[ks], bfr, a, 0, 0, 0);
        }
        acc[cb] = a;
    }

    // ---- epilogue: bias add, store, column stats ----
    float s_c[8], q_c[8];
    #pragma unroll
    for (int cb = 0; cb < 8; cb++) {
        int col = cb * 16 + lrow;
        float bc = bias[col];
        float s = 0.f, q = 0.f;
        #pragma unroll
        for (int r = 0; r < 4; r++) {
            int row = row0 + w * 16 + lkg * 4 + r;
            if (row < N_NODES) {
                float v = acc[cb][r] + bc;
                out[(size_t)row * DIM + col] = v;
                s += v; q += v * v;
            }
        }
        s_c[cb] = s; q_c[cb] = q;
    }
    #pragma unroll
    for (int cb = 0; cb < 8; cb++) {
        s_c[cb] += __shfl_xor(s_c[cb], 16); s_c[cb] += __shfl_xor(s_c[cb], 32);
        q_c[cb] += __shfl_xor(q_c[cb], 16); q_c[cb] += __shfl_xor(q_c[cb], 32);
    }
    __syncthreads();                 // done with A_sm, reuse as reduce scratch
    float* red = reinterpret_cast<float*>(A_sm);   // [4 waves][2][128]
    if (lkg == 0) {
        #pragma unroll
        for (int cb = 0; cb < 8; cb++) {
            red[w * 256 + cb * 16 + lrow]       = s_c[cb];
            red[w * 256 + 128 + cb * 16 + lrow] = q_c[cb];
        }
    }
    __syncthreads();
    float* strep = st_out + (blockIdx.x & (NREP - 1)) * 256;
    if (t < 256) {
        float v = red[t] + red[256 + t] + red[512 + t] + red[768 + t];
        unsafeAtomicAdd(&strep[t], v);
    }
}

// ---------------- stats of xa = relu(BN(x; stA)) — no data write ----------------
__global__ __launch_bounds__(256) void bn_stats_kernel(
    const float* __restrict__ x, const float* __restrict__ st_in,
    const float* __restrict__ bn_g, const float* __restrict__ bn_b,
    float* __restrict__ st_out)
{
    const int t = threadIdx.x;
    const int cg = t & 31;
    float4 sc, sh;
    bn_coef4(st_in, bn_g, bn_b, cg, sc, sh);
    const float4* x4 = reinterpret_cast<const float4*>(x);
    float4 psum = make_float4(0.f, 0.f, 0.f, 0.f);
    float4 psq  = make_float4(0.f, 0.f, 0.f, 0.f);
    const int total = N_NODES * D4;
    const int stride = gridDim.x * 256;
    for (int idx = blockIdx.x * 256 + t; idx < total; idx += stride) {
        float4 v = x4[idx];
        v.x = fmaxf(fmaf(v.x, sc.x, sh.x), 0.f);
        v.y = fmaxf(fmaf(v.y, sc.y, sh.y), 0.f);
        v.z = fmaxf(fmaf(v.z, sc.z, sh.z), 0.f);
        v.w = fmaxf(fmaf(v.w, sc.w, sh.w), 0.f);
        psum.x += v.x; psum.y += v.y; psum.z += v.z; psum.w += v.w;
        psq.x += v.x * v.x; psq.y += v.y * v.y; psq.z += v.z * v.z; psq.w += v.w * v.w;
    }
    __shared__ float4 red[512];
    red[t]       = psum;
    red[256 + t] = psq;
    __syncthreads();
    if (t < 32) {
        float4 s = make_float4(0.f, 0.f, 0.f, 0.f);
        float4 q = make_float4(0.f, 0.f, 0.f, 0.f);
        #pragma unroll
        for (int r = 0; r < 8; r++) {
            float4 a = red[r * 32 + t];
            float4 b = red[256 + r * 32 + t];
            s.x += a.x; s.y += a.y; s.z += a.z; s.w += a.w;
            q.x += b.x; q.y += b.y; q.z += b.z; q.w += b.w;
        }
        float* strep = st_out + (blockIdx.x & (NREP - 1)) * 256;
        float* gs = strep + t * 4;
        float* gq = strep + 128 + t * 4;
        unsafeAtomicAdd(gs + 0, s.x); unsafeAtomicAdd(gs + 1, s.y);
        unsafeAtomicAdd(gs + 2, s.z); unsafeAtomicAdd(gs + 3, s.w);
        unsafeAtomicAdd(gq + 0, q.x); unsafeAtomicAdd(gq + 1, q.y);
        unsafeAtomicAdd(gq + 2, q.z); unsafeAtomicAdd(gq + 3, q.w);
    }
}

// ---------------- h = relu(BN_o(relu(BN_a(x)))) ----------------
// LAST=0: write bf16 h only (next layer input). LAST=1: write fp32 d_out only.
template<int LAST>
__global__ __launch_bounds__(256) void bn_final_kernel(
    const float* __restrict__ x,
    const float* __restrict__ stA, const float* __restrict__ ga, const float* __restrict__ ba,
    const float* __restrict__ stO, const float* __restrict__ go, const float* __restrict__ bo,
    float* __restrict__ y, unsigned short* __restrict__ ybf)
{
    const int t = threadIdx.x;
    const int cg = t & 31;
    float4 sca, sha, sco, sho;
    bn_coef4(stA, ga, ba, cg, sca, sha);
    bn_coef4(stO, go, bo, cg, sco, sho);
    const float4* x4 = reinterpret_cast<const float4*>(x);
    float4* y4 = reinterpret_cast<float4*>(y);
    const int total = N_NODES * D4;
    const int stride = gridDim.x * 256;
    for (int idx = blockIdx.x * 256 + t; idx < total; idx += stride) {
        float4 v = x4[idx];
        v.x = fmaxf(fmaf(v.x, sca.x, sha.x), 0.f);
        v.y = fmaxf(fmaf(v.y, sca.y, sha.y), 0.f);
        v.z = fmaxf(fmaf(v.z, sca.z, sha.z), 0.f);
        v.w = fmaxf(fmaf(v.w, sca.w, sha.w), 0.f);
        v.x = fmaxf(fmaf(v.x, sco.x, sho.x), 0.f);
        v.y = fmaxf(fmaf(v.y, sco.y, sho.y), 0.f);
        v.z = fmaxf(fmaf(v.z, sco.z, sho.z), 0.f);
        v.w = fmaxf(fmaf(v.w, sco.w, sho.w), 0.f);
        if (LAST) {
            y4[idx] = v;
        } else {
            ushort4 u = make_ushort4(f2bf(v.x), f2bf(v.y), f2bf(v.z), f2bf(v.w));
            reinterpret_cast<ushort4*>(ybf)[idx] = u;
        }
    }
}

extern "C" void kernel_launch(void* const* d_in, const int* in_sizes, int n_in,
                              void* d_out, int out_size, void* d_ws, size_t ws_size,
                              hipStream_t stream)
{
    const float* h0    = (const float*)d_in[0];
    const int*   src   = (const int*)d_in[1];
    const int*   dst   = (const int*)d_in[2];
    const float* ew    = (const float*)d_in[3];
    const float* W1    = (const float*)d_in[4];
    const float* b1    = (const float*)d_in[5];
    const float* bn1_g = (const float*)d_in[6];
    const float* bn1_b = (const float*)d_in[7];
    const float* W2    = (const float*)d_in[8];
    const float* b2    = (const float*)d_in[9];
    const float* bna_g = (const float*)d_in[10];
    const float* bna_b = (const float*)d_in[11];
    const float* bno_g = (const float*)d_in[12];
    const float* bno_b = (const float*)d_in[13];

    const size_t ND = (size_t)N_NODES * DIM;
    float* R0     = (float*)d_ws;                         // N*D floats
    float* R1     = R0 + ND;                              // N*D floats
    float* stats  = R1 + ND;                              // 9 * STSZ floats
    int*   counts = (int*)(stats + 9 * STSZ);             // N ints
    int*   offs   = counts + N_NODES;                     // N+1 ints
    int*   cursor = offs + N_NODES + 1;                   // N ints
    int*   bsum   = cursor + N_NODES;                     // 196
    int2*  eperm  = (int2*)(((uintptr_t)(bsum + NBLK_SCAN) + 15) & ~(uintptr_t)15); // E int2
    unsigned short* wtg = (unsigned short*)(eperm + N_EDGES);  // 6*128*128 bf16
    float* hout   = (float*)d_out;

    hipMemsetAsync(stats, 0, 9 * STSZ * sizeof(float), stream);
    wt_kernel<<<(6 * DIM * DIM + 255) / 256, 256, 0, stream>>>(W1, W2, wtg);
    conv0_kernel<<<(N_NODES * D8 + 255) / 256, 256, 0, stream>>>(h0, (unsigned short*)R0);

    const int gemm_grid = (N_NODES + 63) / 64;            // 782
    const int agg_grid  = (N_NODES * 16 + 255) / 256;     // 3125

    for (int i = 0; i < N_LAYERS; i++) {
        const int* srcL = src + (size_t)i * N_EDGES;
        const int* dstL = dst + (size_t)i * N_EDGES;
        const float* ewL = ew + (size_t)i * N_EDGES;
        float* st1 = stats + (size_t)(i * 3 + 0) * STSZ;  // NREP x [sum(128)|sq(128)]
        float* stA = stats + (size_t)(i * 3 + 1) * STSZ;
        float* stO = stats + (size_t)(i * 3 + 2) * STSZ;
        const unsigned short* wt1 = wtg + (size_t)i * DIM * DIM;
        const unsigned short* wt2 = wtg + (size_t)(i + 3) * DIM * DIM;

        // ping-pong regions: even layers h/r in R0, odd layers in R1
        float* Re = (i & 1) ? R1 : R0;
        float* Ro = (i & 1) ? R0 : R1;
        unsigned short* hbf = (unsigned short*)Re;        // first half of Re
        unsigned short* rbf = (unsigned short*)Re + ND;   // second half of Re
        float* x1 = Ro;
        float* x2 = Re;                                   // clobbers hbf+rbf (dead)
        unsigned short* ybf = (unsigned short*)Ro;        // next layer's hbf

        // --- CSR build + bf16 gather aggregation ---
        hipMemsetAsync(counts, 0, N_NODES * sizeof(int), stream);
        hist_kernel<<<EDGE_BLKS, 256, 0, stream>>>(dstL, counts);
        partial_kernel<<<NBLK_SCAN, 256, 0, stream>>>(counts, bsum);
        write_offs_kernel<<<NBLK_SCAN, 256, 0, stream>>>(counts, bsum, offs, cursor);
        fill_kernel<<<NWIN * EDGE_BLKS, 256, 0, stream>>>(srcL, dstL, ewL, cursor, eperm);
        agg_kernel<<<agg_grid, 256, 0, stream>>>(hbf, offs, eperm, rbf);

        gemm_kernel<0><<<gemm_grid, 256, 0, stream>>>(
            rbf, nullptr, nullptr, nullptr, nullptr,
            wt1, b1 + (size_t)i * DIM, x1, st1);

        gemm_kernel<1><<<gemm_grid, 256, 0, stream>>>(
            nullptr, x1, st1, bn1_g + (size_t)i * DIM, bn1_b + (size_t)i * DIM,
            wt2, b2 + (size_t)i * DIM, x2, stA);

        bn_stats_kernel<<<1024, 256, 0, stream>>>(
            x2, stA, bna_g + (size_t)i * DIM, bna_b + (size_t)i * DIM, stO);

        if (i == N_LAYERS - 1) {
            bn_final_kernel<1><<<1024, 256, 0, stream>>>(
                x2, stA, bna_g + (size_t)i * DIM, bna_b + (size_t)i * DIM,
                stO, bno_g + (size_t)i * DIM, bno_b + (size_t)i * DIM, hout, nullptr);
        } else {
            bn_final_kernel<0><<<1024, 256, 0, stream>>>(
                x2, stA, bna_g + (size_t)i * DIM, bna_b + (size_t)i * DIM,
                stO, bno_g + (size_t)i * DIM, bno_b + (size_t)i * DIM, nullptr, ybf);
        }
    }
}

// Round 11
// 715.142 us; speedup vs baseline: 7.1138x; 1.0080x over previous
//
#include <hip/hip_runtime.h>

#define N_NODES 50000
#define DIM 128
#define D4 32            // DIM/4
#define D8 16            // DIM/8 (uint4 = 8 bf16 chunks per row)
#define N_EDGES 800000
#define N_LAYERS 3
#define BN_EPS 1e-5f
#define NBLK_SCAN ((N_NODES + 255) / 256)   // 196
#define NREP 16                              // stat replicas (atomic-chain breaker)
#define STSZ (256 * NREP)                    // floats per stat set
#define NWIN 8                               // fill windows (dst-space partitions)
#define WIN_NODES (N_NODES / NWIN)           // 6250
#define EDGE_BLKS ((N_EDGES + 255) / 256)    // 3125

typedef __attribute__((ext_vector_type(8))) short bf16x8;
typedef __attribute__((ext_vector_type(4))) float f32x4;

// fp32 -> bf16 round-to-nearest-even
__device__ __forceinline__ unsigned short f2bf(float f) {
    unsigned int u = __float_as_uint(f);
    u = (u + 0x7FFFu + ((u >> 16) & 1u)) >> 16;
    return (unsigned short)u;
}
__device__ __forceinline__ unsigned int pack2(float a, float b) {
    return (unsigned int)f2bf(a) | ((unsigned int)f2bf(b) << 16);
}
// fp32 <-> fp16 (RTE via native cast)
__device__ __forceinline__ unsigned short f2h(float f) {
    _Float16 h = (_Float16)f;
    unsigned short u;
    __builtin_memcpy(&u, &h, 2);
    return u;
}
__device__ __forceinline__ float h2f(unsigned short u) {
    _Float16 h;
    __builtin_memcpy(&h, &u, 2);
    return (float)h;
}
__device__ __forceinline__ void bf8_fma(uint4 u, float w, float* acc) {
    acc[0] = fmaf(w, __uint_as_float(u.x << 16), acc[0]);
    acc[1] = fmaf(w, __uint_as_float(u.x & 0xFFFF0000u), acc[1]);
    acc[2] = fmaf(w, __uint_as_float(u.y << 16), acc[2]);
    acc[3] = fmaf(w, __uint_as_float(u.y & 0xFFFF0000u), acc[3]);
    acc[4] = fmaf(w, __uint_as_float(u.z << 16), acc[4]);
    acc[5] = fmaf(w, __uint_as_float(u.z & 0xFFFF0000u), acc[5]);
    acc[6] = fmaf(w, __uint_as_float(u.w << 16), acc[6]);
    acc[7] = fmaf(w, __uint_as_float(u.w & 0xFFFF0000u), acc[7]);
}

// scale/shift from raw BN stats
__device__ __forceinline__ void bn_coef(float sum, float sq, float g, float b,
                                        float& sc, float& sh) {
    float mean = sum * (1.f / N_NODES);
    float var  = sq * (1.f / N_NODES) - mean * mean;
    float rstd = rsqrtf(var + BN_EPS);
    sc = g * rstd;
    sh = b - mean * sc;
}

// sum NREP replicas, then coefs (vector form; cg = float4 column group)
__device__ __forceinline__ void bn_coef4(const float* st,
                                         const float* g, const float* b, int cg,
                                         float4& sc, float4& sh) {
    float4 s = make_float4(0.f, 0.f, 0.f, 0.f);
    float4 q = make_float4(0.f, 0.f, 0.f, 0.f);
    #pragma unroll
    for (int r = 0; r < NREP; r++) {
        const float4* p = reinterpret_cast<const float4*>(st + r * 256);
        float4 a = p[cg];          // sum part
        float4 c = p[32 + cg];     // sq part
        s.x += a.x; s.y += a.y; s.z += a.z; s.w += a.w;
        q.x += c.x; q.y += c.y; q.z += c.z; q.w += c.w;
    }
    float4 gg = reinterpret_cast<const float4*>(g)[cg];
    float4 bb = reinterpret_cast<const float4*>(b)[cg];
    bn_coef(s.x, q.x, gg.x, bb.x, sc.x, sh.x);
    bn_coef(s.y, q.y, gg.y, bb.y, sc.y, sh.y);
    bn_coef(s.z, q.z, gg.z, bb.z, sc.z, sh.z);
    bn_coef(s.w, q.w, gg.w, bb.w, sc.w, sh.w);
}

// ---------------- W transpose + bf16 convert (once per launch, all 6 weights) ----
__global__ __launch_bounds__(256) void wt_kernel(
    const float* __restrict__ W1, const float* __restrict__ W2,
    unsigned short* __restrict__ wtg)
{
    int tid = blockIdx.x * 256 + threadIdx.x;          // 6*16384 total
    if (tid >= 6 * DIM * DIM) return;
    int m = tid >> 14;           // /16384
    int r = tid & 16383;
    int c = r >> 7;              // output row (col of W)
    int k = r & 127;             // output col (row of W)
    const float* src = (m < 3) ? (W1 + (size_t)m * DIM * DIM)
                               : (W2 + (size_t)(m - 3) * DIM * DIM);
    wtg[tid] = f2bf(src[k * DIM + c]);
}

// ---------------- h0 fp32 -> bf16 (layer 0 only) ----------------
__global__ __launch_bounds__(256) void conv0_kernel(
    const float* __restrict__ h, unsigned short* __restrict__ hbf)
{
    int idx = blockIdx.x * 256 + threadIdx.x;          // per 8 elems
    if (idx >= N_NODES * D8) return;
    const float4* h4 = reinterpret_cast<const float4*>(h);
    float4 a = h4[idx * 2], b = h4[idx * 2 + 1];
    uint4 p;
    p.x = pack2(a.x, a.y); p.y = pack2(a.z, a.w);
    p.z = pack2(b.x, b.y); p.w = pack2(b.z, b.w);
    reinterpret_cast<uint4*>(hbf)[idx] = p;
}

// ---------------- CSR build: histogram of dst ----------------
__global__ __launch_bounds__(256) void hist_kernel(
    const int* __restrict__ dst, int* __restrict__ counts)
{
    int e = blockIdx.x * 256 + threadIdx.x;
    if (e < N_EDGES) atomicAdd(&counts[dst[e]], 1);
}

// ---------------- scan stage 1: per-256-chunk sums ----------------
__global__ __launch_bounds__(256) void partial_kernel(
    const int* __restrict__ counts, int* __restrict__ bsum)
{
    __shared__ int s[256];
    int idx = blockIdx.x * 256 + threadIdx.x;
    int v = (idx < N_NODES) ? counts[idx] : 0;
    s[threadIdx.x] = v;
    __syncthreads();
    #pragma unroll
    for (int off = 128; off > 0; off >>= 1) {
        if (threadIdx.x < off) s[threadIdx.x] += s[threadIdx.x + off];
        __syncthreads();
    }
    if (threadIdx.x == 0) bsum[blockIdx.x] = s[0];
}

// ---- scan stage 2 (fused): inline scan of bsum + per-chunk scan + base ----
// also re-zeroes counts for the next layer's histogram (saves a memset dispatch)
__global__ __launch_bounds__(256) void write_offs_kernel(
    int* __restrict__ counts, const int* __restrict__ bsum,
    int* __restrict__ offsets, int* __restrict__ cursor)
{
    __shared__ int sb[256];
    __shared__ int s[256];
    int t = threadIdx.x;
    // every block redundantly scans the 196 block sums (cheap, removes a launch)
    int bv = (t < NBLK_SCAN) ? bsum[t] : 0;
    sb[t] = bv;
    __syncthreads();
    #pragma unroll
    for (int off = 1; off < 256; off <<= 1) {
        int u = (t >= off) ? sb[t - off] : 0;
        __syncthreads();
        sb[t] += u;
        __syncthreads();
    }
    int base = (blockIdx.x == 0) ? 0 : sb[blockIdx.x - 1];   // exclusive block prefix
    if (blockIdx.x == 0 && t == 0) offsets[N_NODES] = sb[255];

    int idx = blockIdx.x * 256 + t;
    int v = (idx < N_NODES) ? counts[idx] : 0;
    s[t] = v;
    __syncthreads();
    #pragma unroll
    for (int off = 1; off < 256; off <<= 1) {
        int u = (t >= off) ? s[t - off] : 0;
        __syncthreads();
        s[t] += u;
        __syncthreads();
    }
    int ex = s[t] - v + base;
    if (idx < N_NODES) { offsets[idx] = ex; cursor[idx] = ex; counts[idx] = 0; }
}

// ---------------- CSR fill, 4B records, dst-windowed ----------------
// record = (src << 16) | fp16(w); scatter bytes halved vs int2 (fewer dirty
// lines -> fewer partial-line RMW round-trips at the memory side).
__global__ __launch_bounds__(256) void fill_kernel(
    const int* __restrict__ src, const int* __restrict__ dst,
    const float* __restrict__ ew, int* __restrict__ cursor,
    unsigned int* __restrict__ eperm)
{
    int w = blockIdx.x / EDGE_BLKS;
    int e = (blockIdx.x - w * EDGE_BLKS) * 256 + threadIdx.x;
    if (e >= N_EDGES) return;
    int d = dst[e];
    int lo = w * WIN_NODES;
    if (d < lo || d >= lo + WIN_NODES) return;
    int pos = atomicAdd(&cursor[d], 1);
    eperm[pos] = ((unsigned int)src[e] << 16) | (unsigned int)f2h(ew[e]);
}

// ---- aggregate + self: rbf[n] = bf16( h[n] + sum_{e: dst=n} w_e * h[src_e] ) ----
// 16 lanes per node, bf16 gather (uint4 = 8 bf16 per lane), fp32 accumulate.
__global__ __launch_bounds__(256) void agg_kernel(
    const unsigned short* __restrict__ hbf, const int* __restrict__ offsets,
    const unsigned int* __restrict__ eperm, unsigned short* __restrict__ rbf)
{
    int gid = blockIdx.x * 256 + threadIdx.x;
    int node = gid >> 4;
    if (node >= N_NODES) return;
    int lane = gid & 15;
    const uint4* h4 = reinterpret_cast<const uint4*>(hbf);
    int cidx = node * D8 + lane;
    float acc[8] = {0.f, 0.f, 0.f, 0.f, 0.f, 0.f, 0.f, 0.f};
    bf8_fma(h4[cidx], 1.0f, acc);                 // self term (eps = 0)
    int beg = offsets[node], end = offsets[node + 1];
    for (int j = beg; j < end; j++) {
        unsigned int rec = eperm[j];
        float w = h2f((unsigned short)(rec & 0xFFFFu));
        bf8_fma(h4[(rec >> 16) * D8 + lane], w, acc);
    }
    uint4 p;
    p.x = pack2(acc[0], acc[1]); p.y = pack2(acc[2], acc[3]);
    p.z = pack2(acc[4], acc[5]); p.w = pack2(acc[6], acc[7]);
    reinterpret_cast<uint4*>(rbf)[cidx] = p;
}

// ---------------- MFMA GEMM: out = f(in) @ W + bias, + column stats ----------------
// MODE 0: in = rbf (pre-staged bf16)     (GEMM1)
// MODE 1: in = relu(BN(A; st,g,b))       (GEMM2: BN1+ReLU fused on staging)
template<int MODE>
__global__ __launch_bounds__(256) void gemm_kernel(
    const unsigned short* __restrict__ Abf, const float* __restrict__ A,
    const float* __restrict__ st_in, const float* __restrict__ bn_g,
    const float* __restrict__ bn_b,
    const unsigned short* __restrict__ Wt, const float* __restrict__ bias,
    float* __restrict__ out, float* __restrict__ st_out)
{
    __shared__ unsigned short A_sm[64 * DIM];    // 16 KB bf16, XOR-swizzled
    __shared__ unsigned short W_sm[DIM * DIM];   // 32 KB bf16 W^T, XOR-swizzled
    __shared__ float2 scsh[DIM];                 // BN coefs (MODE 1)

    const int t = threadIdx.x;
    const int row0 = blockIdx.x * 64;

    if (MODE == 1) {
        if (t < 128) {
            float ssum = 0.f, ssq = 0.f;
            #pragma unroll
            for (int r = 0; r < NREP; r++) {
                ssum += st_in[r * 256 + t];
                ssq  += st_in[r * 256 + 128 + t];
            }
            float sc, sh;
            bn_coef(ssum, ssq, bn_g[t], bn_b[t], sc, sh);
            scsh[t] = make_float2(sc, sh);
        }
        __syncthreads();
    }

    // ---- stage W^T (already bf16, c-major): 2048 16B chunks ----
    {
        const uint4* wsrc = reinterpret_cast<const uint4*>(Wt);
        #pragma unroll
        for (int j = 0; j < 8; j++) {
            int id = t + j * 256;            // 0..2047
            int c  = id >> 4;
            int kc = id & 15;
            int sidx = (c * DIM + kc * 8) ^ ((c & 7) << 3);
            *reinterpret_cast<uint4*>(&W_sm[sidx]) = wsrc[id];
        }
    }

    // ---- stage A tile (swizzled) ----
    if (MODE == 0) {
        const uint4* asrc = reinterpret_cast<const uint4*>(Abf);
        #pragma unroll
        for (int j = 0; j < 4; j++) {
            int id = t + j * 256;            // 0..1023
            int r  = id >> 4;                // tile row 0..63
            int kc = id & 15;
            int row = row0 + r;
            uint4 u = make_uint4(0u, 0u, 0u, 0u);
            if (row < N_NODES) u = asrc[row * D8 + kc];
            int sidx = (r * DIM + kc * 8) ^ ((r & 7) << 3);
            *reinterpret_cast<uint4*>(&A_sm[sidx]) = u;
        }
    } else {
        const float4* A4 = reinterpret_cast<const float4*>(A);
        #pragma unroll
        for (int j = 0; j < 8; j++) {
            int id = t + j * 256;            // 0..2047
            int r  = id >> 5;                // tile row 0..63
            int q  = id & 31;                // float4 col group
            int row = row0 + r;
            float4 v = make_float4(0.f, 0.f, 0.f, 0.f);
            if (row < N_NODES) {
                float4 a = A4[(size_t)row * D4 + q];
                float2 c0 = scsh[q * 4 + 0], c1 = scsh[q * 4 + 1];
                float2 c2 = scsh[q * 4 + 2], c3 = scsh[q * 4 + 3];
                v.x = fmaxf(fmaf(a.x, c0.x, c0.y), 0.f);
                v.y = fmaxf(fmaf(a.y, c1.x, c1.y), 0.f);
                v.z = fmaxf(fmaf(a.z, c2.x, c2.y), 0.f);
                v.w = fmaxf(fmaf(a.w, c3.x, c3.y), 0.f);
            }
            ushort4 u = make_ushort4(f2bf(v.x), f2bf(v.y), f2bf(v.z), f2bf(v.w));
            int sidx = (r * DIM + q * 4) ^ ((r & 7) << 3);
            *reinterpret_cast<ushort4*>(&A_sm[sidx]) = u;
        }
    }
    __syncthreads();

    // ---- MFMA: wave w owns rows w*16..w*16+15, all 8 col-blocks ----
    const int w    = t >> 6;
    const int lane = t & 63;
    const int lrow = lane & 15;
    const int lkg  = lane >> 4;
    const int arow = w * 16 + lrow;

    bf16x8 afr[4];
    #pragma unroll
    for (int ks = 0; ks < 4; ks++) {
        int k = ks * 32 + lkg * 8;
        int idx = (arow * DIM + k) ^ ((arow & 7) << 3);
        afr[ks] = *reinterpret_cast<const bf16x8*>(&A_sm[idx]);
    }

    f32x4 acc[8];
    #pragma unroll
    for (int cb = 0; cb < 8; cb++) {
        f32x4 a = {0.f, 0.f, 0.f, 0.f};
        int col = cb * 16 + lrow;
        #pragma unroll
        for (int ks = 0; ks < 4; ks++) {
            int k = ks * 32 + lkg * 8;
            int widx = (col * DIM + k) ^ ((col & 7) << 3);
            bf16x8 bfr = *reinterpret_cast<const bf16x8*>(&W_sm[widx]);
            a = __builtin_amdgcn_mfma_f32_16x16x32_bf16(afr[ks], bfr, a, 0, 0, 0);
        }
        acc[cb] = a;
    }

    // ---- epilogue: bias add, store, column stats ----
    float s_c[8], q_c[8];
    #pragma unroll
    for (int cb = 0; cb < 8; cb++) {
        int col = cb * 16 + lrow;
        float bc = bias[col];
        float s = 0.f, q = 0.f;
        #pragma unroll
        for (int r = 0; r < 4; r++) {
            int row = row0 + w * 16 + lkg * 4 + r;
            if (row < N_NODES) {
                float v = acc[cb][r] + bc;
                out[(size_t)row * DIM + col] = v;
                s += v; q += v * v;
            }
        }
        s_c[cb] = s; q_c[cb] = q;
    }
    #pragma unroll
    for (int cb = 0; cb < 8; cb++) {
        s_c[cb] += __shfl_xor(s_c[cb], 16); s_c[cb] += __shfl_xor(s_c[cb], 32);
        q_c[cb] += __shfl_xor(q_c[cb], 16); q_c[cb] += __shfl_xor(q_c[cb], 32);
    }
    __syncthreads();                 // done with A_sm, reuse as reduce scratch
    float* red = reinterpret_cast<float*>(A_sm);   // [4 waves][2][128]
    if (lkg == 0) {
        #pragma unroll
        for (int cb = 0; cb < 8; cb++) {
            red[w * 256 + cb * 16 + lrow]       = s_c[cb];
            red[w * 256 + 128 + cb * 16 + lrow] = q_c[cb];
        }
    }
    __syncthreads();
    float* strep = st_out + (blockIdx.x & (NREP - 1)) * 256;
    if (t < 256) {
        float v = red[t] + red[256 + t] + red[512 + t] + red[768 + t];
        unsafeAtomicAdd(&strep[t], v);
    }
}

// ---------------- stats of xa = relu(BN(x; stA)) — no data write ----------------
__global__ __launch_bounds__(256) void bn_stats_kernel(
    const float* __restrict__ x, const float* __restrict__ st_in,
    const float* __restrict__ bn_g, const float* __restrict__ bn_b,
    float* __restrict__ st_out)
{
    const int t = threadIdx.x;
    const int cg = t & 31;
    float4 sc, sh;
    bn_coef4(st_in, bn_g, bn_b, cg, sc, sh);
    const float4* x4 = reinterpret_cast<const float4*>(x);
    float4 psum = make_float4(0.f, 0.f, 0.f, 0.f);
    float4 psq  = make_float4(0.f, 0.f, 0.f, 0.f);
    const int total = N_NODES * D4;
    const int stride = gridDim.x * 256;
    for (int idx = blockIdx.x * 256 + t; idx < total; idx += stride) {
        float4 v = x4[idx];
        v.x = fmaxf(fmaf(v.x, sc.x, sh.x), 0.f);
        v.y = fmaxf(fmaf(v.y, sc.y, sh.y), 0.f);
        v.z = fmaxf(fmaf(v.z, sc.z, sh.z), 0.f);
        v.w = fmaxf(fmaf(v.w, sc.w, sh.w), 0.f);
        psum.x += v.x; psum.y += v.y; psum.z += v.z; psum.w += v.w;
        psq.x += v.x * v.x; psq.y += v.y * v.y; psq.z += v.z * v.z; psq.w += v.w * v.w;
    }
    __shared__ float4 red[512];
    red[t]       = psum;
    red[256 + t] = psq;
    __syncthreads();
    if (t < 32) {
        float4 s = make_float4(0.f, 0.f, 0.f, 0.f);
        float4 q = make_float4(0.f, 0.f, 0.f, 0.f);
        #pragma unroll
        for (int r = 0; r < 8; r++) {
            float4 a = red[r * 32 + t];
            float4 b = red[256 + r * 32 + t];
            s.x += a.x; s.y += a.y; s.z += a.z; s.w += a.w;
            q.x += b.x; q.y += b.y; q.z += b.z; q.w += b.w;
        }
        float* strep = st_out + (blockIdx.x & (NREP - 1)) * 256;
        float* gs = strep + t * 4;
        float* gq = strep + 128 + t * 4;
        unsafeAtomicAdd(gs + 0, s.x); unsafeAtomicAdd(gs + 1, s.y);
        unsafeAtomicAdd(gs + 2, s.z); unsafeAtomicAdd(gs + 3, s.w);
        unsafeAtomicAdd(gq + 0, q.x); unsafeAtomicAdd(gq + 1, q.y);
        unsafeAtomicAdd(gq + 2, q.z); unsafeAtomicAdd(gq + 3, q.w);
    }
}

// ---------------- h = relu(BN_o(relu(BN_a(x)))) ----------------
// LAST=0: write bf16 h only (next layer input). LAST=1: write fp32 d_out only.
template<int LAST>
__global__ __launch_bounds__(256) void bn_final_kernel(
    const float* __restrict__ x,
    const float* __restrict__ stA, const float* __restrict__ ga, const float* __restrict__ ba,
    const float* __restrict__ stO, const float* __restrict__ go, const float* __restrict__ bo,
    float* __restrict__ y, unsigned short* __restrict__ ybf)
{
    const int t = threadIdx.x;
    const int cg = t & 31;
    float4 sca, sha, sco, sho;
    bn_coef4(stA, ga, ba, cg, sca, sha);
    bn_coef4(stO, go, bo, cg, sco, sho);
    const float4* x4 = reinterpret_cast<const float4*>(x);
    float4* y4 = reinterpret_cast<float4*>(y);
    const int total = N_NODES * D4;
    const int stride = gridDim.x * 256;
    for (int idx = blockIdx.x * 256 + t; idx < total; idx += stride) {
        float4 v = x4[idx];
        v.x = fmaxf(fmaf(v.x, sca.x, sha.x), 0.f);
        v.y = fmaxf(fmaf(v.y, sca.y, sha.y), 0.f);
        v.z = fmaxf(fmaf(v.z, sca.z, sha.z), 0.f);
        v.w = fmaxf(fmaf(v.w, sca.w, sha.w), 0.f);
        v.x = fmaxf(fmaf(v.x, sco.x, sho.x), 0.f);
        v.y = fmaxf(fmaf(v.y, sco.y, sho.y), 0.f);
        v.z = fmaxf(fmaf(v.z, sco.z, sho.z), 0.f);
        v.w = fmaxf(fmaf(v.w, sco.w, sho.w), 0.f);
        if (LAST) {
            y4[idx] = v;
        } else {
            ushort4 u = make_ushort4(f2bf(v.x), f2bf(v.y), f2bf(v.z), f2bf(v.w));
            reinterpret_cast<ushort4*>(ybf)[idx] = u;
        }
    }
}

extern "C" void kernel_launch(void* const* d_in, const int* in_sizes, int n_in,
                              void* d_out, int out_size, void* d_ws, size_t ws_size,
                              hipStream_t stream)
{
    const float* h0    = (const float*)d_in[0];
    const int*   src   = (const int*)d_in[1];
    const int*   dst   = (const int*)d_in[2];
    const float* ew    = (const float*)d_in[3];
    const float* W1    = (const float*)d_in[4];
    const float* b1    = (const float*)d_in[5];
    const float* bn1_g = (const float*)d_in[6];
    const float* bn1_b = (const float*)d_in[7];
    const float* W2    = (const float*)d_in[8];
    const float* b2    = (const float*)d_in[9];
    const float* bna_g = (const float*)d_in[10];
    const float* bna_b = (const float*)d_in[11];
    const float* bno_g = (const float*)d_in[12];
    const float* bno_b = (const float*)d_in[13];

    const size_t ND = (size_t)N_NODES * DIM;
    float* R0     = (float*)d_ws;                         // N*D floats
    float* R1     = R0 + ND;                              // N*D floats
    float* stats  = R1 + ND;                              // 9 * STSZ floats
    int*   counts = (int*)(stats + 9 * STSZ);             // N ints
    int*   offs   = counts + N_NODES;                     // N+1 ints
    int*   cursor = offs + N_NODES + 1;                   // N ints
    int*   bsum   = cursor + N_NODES;                     // 196
    unsigned int* eperm = (unsigned int*)(bsum + NBLK_SCAN);   // E uints (4B records)
    unsigned short* wtg = (unsigned short*)(eperm + N_EDGES);  // 6*128*128 bf16
    float* hout   = (float*)d_out;

    hipMemsetAsync(stats, 0, 9 * STSZ * sizeof(float), stream);
    hipMemsetAsync(counts, 0, N_NODES * sizeof(int), stream);   // layer 0 (layers 1,2 re-zeroed in write_offs)
    wt_kernel<<<(6 * DIM * DIM + 255) / 256, 256, 0, stream>>>(W1, W2, wtg);
    conv0_kernel<<<(N_NODES * D8 + 255) / 256, 256, 0, stream>>>(h0, (unsigned short*)R0);

    const int gemm_grid = (N_NODES + 63) / 64;            // 782
    const int agg_grid  = (N_NODES * 16 + 255) / 256;     // 3125

    for (int i = 0; i < N_LAYERS; i++) {
        const int* srcL = src + (size_t)i * N_EDGES;
        const int* dstL = dst + (size_t)i * N_EDGES;
        const float* ewL = ew + (size_t)i * N_EDGES;
        float* st1 = stats + (size_t)(i * 3 + 0) * STSZ;  // NREP x [sum(128)|sq(128)]
        float* stA = stats + (size_t)(i * 3 + 1) * STSZ;
        float* stO = stats + (size_t)(i * 3 + 2) * STSZ;
        const unsigned short* wt1 = wtg + (size_t)i * DIM * DIM;
        const unsigned short* wt2 = wtg + (size_t)(i + 3) * DIM * DIM;

        // ping-pong regions: even layers h/r in R0, odd layers in R1
        float* Re = (i & 1) ? R1 : R0;
        float* Ro = (i & 1) ? R0 : R1;
        unsigned short* hbf = (unsigned short*)Re;        // first half of Re
        unsigned short* rbf = (unsigned short*)Re + ND;   // second half of Re
        float* x1 = Ro;
        float* x2 = Re;                                   // clobbers hbf+rbf (dead)
        unsigned short* ybf = (unsigned short*)Ro;        // next layer's hbf

        // --- CSR build + bf16 gather aggregation ---
        hist_kernel<<<EDGE_BLKS, 256, 0, stream>>>(dstL, counts);
        partial_kernel<<<NBLK_SCAN, 256, 0, stream>>>(counts, bsum);
        write_offs_kernel<<<NBLK_SCAN, 256, 0, stream>>>(counts, bsum, offs, cursor);
        fill_kernel<<<NWIN * EDGE_BLKS, 256, 0, stream>>>(srcL, dstL, ewL, cursor, eperm);
        agg_kernel<<<agg_grid, 256, 0, stream>>>(hbf, offs, eperm, rbf);

        gemm_kernel<0><<<gemm_grid, 256, 0, stream>>>(
            rbf, nullptr, nullptr, nullptr, nullptr,
            wt1, b1 + (size_t)i * DIM, x1, st1);

        gemm_kernel<1><<<gemm_grid, 256, 0, stream>>>(
            nullptr, x1, st1, bn1_g + (size_t)i * DIM, bn1_b + (size_t)i * DIM,
            wt2, b2 + (size_t)i * DIM, x2, stA);

        bn_stats_kernel<<<1024, 256, 0, stream>>>(
            x2, stA, bna_g + (size_t)i * DIM, bna_b + (size_t)i * DIM, stO);

        if (i == N_LAYERS - 1) {
            bn_final_kernel<1><<<1024, 256, 0, stream>>>(
                x2, stA, bna_g + (size_t)i * DIM, bna_b + (size_t)i * DIM,
                stO, bno_g + (size_t)i * DIM, bno_b + (size_t)i * DIM, hout, nullptr);
        } else {
            bn_final_kernel<0><<<1024, 256, 0, stream>>>(
                x2, stA, bna_g + (size_t)i * DIM, bna_b + (size_t)i * DIM,
                stO, bno_g + (size_t)i * DIM, bno_b + (size_t)i * DIM, nullptr, ybf);
        }
    }
}